// Round 13
// baseline (942.360 us; speedup 1.0000x reference)
//
#include <hip/hip_runtime.h>
#include <hip/hip_bf16.h>

typedef unsigned short u16;
typedef __attribute__((ext_vector_type(8))) short bf16x8;
typedef __attribute__((ext_vector_type(8))) unsigned short us8;
typedef __attribute__((ext_vector_type(4))) float f32x4;

#define T_Q 32
#define T_K 48
#define NB 64
#define HDIM 1024
#define MASK_FILL -65504.0f
#define LSTM_BLOCKS 64

__device__ __forceinline__ float bf2f(u16 v){
  union { unsigned u; float f; } x; x.u = ((unsigned)v) << 16; return x.f;
}
__device__ __forceinline__ u16 f2bf(float f){
  union { float f; unsigned u; } x; x.f = f;
  return (u16)((x.u + 0x7FFFu + ((x.u >> 16) & 1u)) >> 16);
}
__device__ __forceinline__ float sigm(float x){
  return __builtin_amdgcn_rcpf(1.f + __expf(-x));
}
__device__ __forceinline__ float tanh_f(float x){
  float e = __expf(2.f * x);
  return fmaf(-2.f, __builtin_amdgcn_rcpf(e + 1.f), 1.f);  // graceful at +/-inf
}

// Cross-XCD coherent sync-path ops (sc0 = bypass L0/L1, sc1 = bypass local L2;
// coherence point = Infinity Cache). Used ONLY for the tiny publish/flag path.
// h DATA loads are normal cached loads against write-once rotating buffers (r6).
// r7 lesson: one global poller per block. r10: wave-specialized staging regressed.
// r11: gemm128 loses to gemm64 here (TLP). r12: dual-chain regressed (2x sync).
// r13: fill the publish->detect idle with INDEPENDENT work (xp GEMM) instead.
__device__ __forceinline__ void st_b32_cc(u16* a, unsigned v){
  asm volatile("global_store_dword %0, %1, off sc0 sc1" :: "v"(a), "v"(v) : "memory");
}
__device__ __forceinline__ void st_flag(int* a, int v){
  asm volatile("global_store_dword %0, %1, off sc0 sc1" :: "v"(a), "v"(v) : "memory");
}
__device__ __forceinline__ int ld_flag(const int* a){
  int r;
  asm volatile("global_load_dword %0, %1, off sc0 sc1\n\ts_waitcnt vmcnt(0)"
               : "=v"(r) : "v"(a) : "memory");
  return r;
}

#define MFMA16(A,B,C) __builtin_amdgcn_mfma_f32_16x16x32_bf16(A,B,C,0,0,0)

// ---------------- prep kernels ----------------

__global__ void conv_f2b(const float* __restrict__ s, u16* __restrict__ d){
  size_t i = ((size_t)blockIdx.x * 256 + threadIdx.x) * 4;
  float4 v = *(const float4*)(s + i);
  ushort4 o; o.x = f2bf(v.x); o.y = f2bf(v.y); o.z = f2bf(v.z); o.w = f2bf(v.w);
  *(ushort4*)(d + i) = o;
}

__global__ void gather_x(const int* __restrict__ tok, const float* __restrict__ emb,
                         u16* __restrict__ x){
  int r = blockIdx.x;                      // r = t*64 + b
  int token = tok[r];
  float4 v = ((const float4*)(emb + (size_t)token * HDIM))[threadIdx.x];
  ushort4 o; o.x = f2bf(v.x); o.y = f2bf(v.y); o.z = f2bf(v.z); o.w = f2bf(v.w);
  ((ushort4*)(x + (size_t)r * HDIM))[threadIdx.x] = o;
}

__global__ void make_keys(const float* __restrict__ a, const float* __restrict__ b,
                          u16* __restrict__ o){
  size_t i = ((size_t)blockIdx.x * 256 + threadIdx.x) * 4;
  float4 va = *(const float4*)(a + i);
  float4 vb = *(const float4*)(b + i);
  ushort4 vo;
  vo.x = f2bf(va.x + vb.x);
  vo.y = f2bf(va.y + vb.y);
  vo.z = f2bf(va.z + vb.z);
  vo.w = f2bf(va.w + vb.w);
  *(ushort4*)(o + i) = vo;
}

__global__ void prep_small(const float* __restrict__ vatt, const float* __restrict__ ns,
                           const float* __restrict__ nb,
                           float* __restrict__ vhat, float* __restrict__ nbias){
  __shared__ float wred[4];
  int t = threadIdx.x, lane = t & 63, w = t >> 6;
  float vv[4]; float s = 0.f;
  #pragma unroll
  for (int j = 0; j < 4; j++){ vv[j] = vatt[t*4 + j]; s += vv[j]*vv[j]; }
  #pragma unroll
  for (int m = 32; m >= 1; m >>= 1) s += __shfl_xor(s, m);
  if (lane == 0) wred[w] = s;
  __syncthreads();
  float tot = wred[0] + wred[1] + wred[2] + wred[3];
  float scale = ns[0] / sqrtf(tot);
  #pragma unroll
  for (int j = 0; j < 4; j++) vhat[t*4 + j] = vv[j] * scale;
  #pragma unroll
  for (int j = 0; j < 4; j++){ int i = t + 256*j; nbias[i] = nb[i]; }
}

__global__ void prep_bsum(const float* __restrict__ bih, const float* __restrict__ bhh,
                          float* __restrict__ bias_sum){
  int i = blockIdx.x * 256 + threadIdx.x;
  bias_sum[i] = bih[i] + bhh[i];
}

// ---------------- generic bf16 GEMM (r6/r9-proven 64x64 tile) ----------------
// C[M][N] = A[M][K] * W[N][K]^T + bias. OB=1 -> bf16 out, OB=0 -> f32 out.

template<int OB>
__global__ __launch_bounds__(256) void gemm_bf16(
  const u16* __restrict__ A, const u16* __restrict__ W,
  const float* __restrict__ bias, void* __restrict__ Cv,
  int M, int N, int K)
{
  __shared__ __align__(16) u16 As[4][66][8];   // [kc][row][8], kc-stride 1056B
  __shared__ __align__(16) u16 Bs[4][66][8];
  const int t = threadIdx.x;
  const int m0 = blockIdx.y * 64, n0 = blockIdx.x * 64;
  const int lane = t & 63, w = t >> 6;
  const int wm = (w >> 1) * 32, wn = (w & 1) * 32;
  const int lr = lane & 15, g = lane >> 4;
  const int lrow = t >> 2, lkc = t & 3;
  f32x4 acc00 = {0,0,0,0}, acc01 = {0,0,0,0}, acc10 = {0,0,0,0}, acc11 = {0,0,0,0};
  const u16* aptr = A + (size_t)(m0 + lrow) * K + lkc * 8;
  const u16* wptr = W + (size_t)(n0 + lrow) * K + lkc * 8;
  for (int k0 = 0; k0 < K; k0 += 32){
    *(bf16x8*)(&As[lkc][lrow][0]) = *(const bf16x8*)(aptr + k0);
    *(bf16x8*)(&Bs[lkc][lrow][0]) = *(const bf16x8*)(wptr + k0);
    __syncthreads();
    bf16x8 a0 = *(const bf16x8*)(&As[g][wm      + lr][0]);
    bf16x8 a1 = *(const bf16x8*)(&As[g][wm + 16 + lr][0]);
    bf16x8 b0 = *(const bf16x8*)(&Bs[g][wn      + lr][0]);
    bf16x8 b1 = *(const bf16x8*)(&Bs[g][wn + 16 + lr][0]);
    acc00 = MFMA16(a0, b0, acc00);
    acc01 = MFMA16(a0, b1, acc01);
    acc10 = MFMA16(a1, b0, acc10);
    acc11 = MFMA16(a1, b1, acc11);
    __syncthreads();
  }
  // C/D layout: col = lane&15, row = (lane>>4)*4 + reg   [m89-verified]
  const int rb = m0 + wm + g * 4;
  const int cb = n0 + wn + lr;
  float bv0 = bias ? bias[cb]      : 0.f;
  float bv1 = bias ? bias[cb + 16] : 0.f;
  #pragma unroll
  for (int r = 0; r < 4; r++){
    float v00 = acc00[r] + bv0, v01 = acc01[r] + bv1;
    float v10 = acc10[r] + bv0, v11 = acc11[r] + bv1;
    if (OB){
      u16* C = (u16*)Cv;
      C[(size_t)(rb + r)      * N + cb]      = f2bf(v00);
      C[(size_t)(rb + r)      * N + cb + 16] = f2bf(v01);
      C[(size_t)(rb + 16 + r) * N + cb]      = f2bf(v10);
      C[(size_t)(rb + 16 + r) * N + cb + 16] = f2bf(v11);
    } else {
      float* C = (float*)Cv;
      C[(size_t)(rb + r)      * N + cb]      = v00;
      C[(size_t)(rb + r)      * N + cb + 16] = v01;
      C[(size_t)(rb + 16 + r) * N + cb]      = v10;
      C[(size_t)(rb + 16 + r) * N + cb + 16] = v11;
    }
  }
}

// ---------------- persistent LSTM (r13: fused xp GEMM in the idle window) ----------------
// r9 structure verbatim (best measured: 201us) PLUS: each step first computes its
// own xp slice gates_x = x_t * Wih_slice^T (no recurrence dependence!) BEFORE the
// flag poll -- this work fills the publish->L3->detect window that was ~80% stall
// (MfmaUtil 3.2%). Eliminates the standalone 57us xp GEMM and its 16MB buffer.
// xp fragment patterns identical to the verified h*Whh^T path; bias (bsum) moves
// to 8 preloaded registers in the pointwise; gl = acc_h + acc_x.

__global__ __launch_bounds__(512, 1) void lstm_persistent(
  const float* __restrict__ Whh, const u16* __restrict__ x_bf,
  const u16* __restrict__ Wih_bf, const float* __restrict__ bsum,
  u16* __restrict__ hsteps,
  u16* __restrict__ qbuf, float* __restrict__ out0,
  int* __restrict__ flags)
{
  extern __shared__ char smem[];
  u16*  wlds = (u16*)smem;                    // [4][32][16][32] bf16 (128KB)
  float* gl  = (float*)(smem + 131072);       // [4][64][16] f32 (16KB)
  volatile int* lds_ready = (volatile int*)(smem + 147456);  // [8]

  const int tid = threadIdx.x;
  const int c0 = blockIdx.x * 16;
  const int lane = tid & 63, w = tid >> 6;    // 8 waves
  const int gate = w & 3, msub = w >> 2;      // wave -> (gate, m-half)
  const int lr = lane & 15, g = lane >> 4;

  if (tid < 8) lds_ready[tid] = 0;

  // ---- one-time: Whh slice f32 -> bf16 -> LDS ----
  #pragma unroll
  for (int i = 0; i < 16; i++){
    int e = (i * 512 + tid) * 8;               // element in 64x1024 slice
    int R = e >> 10, k = e & 1023;
    int gg = R >> 4, rr = R & 15, tt = k >> 5, kk = k & 31;
    const float* src = Whh + (size_t)((gg << 10) + c0 + rr) * 1024 + k;
    float4 v0 = *(const float4*)(src);
    float4 v1 = *(const float4*)(src + 4);
    u16* dst = wlds + (((gg * 32 + tt) * 16 + rr) * 32 + kk);
    ushort4 o0, o1;
    o0.x = f2bf(v0.x); o0.y = f2bf(v0.y); o0.z = f2bf(v0.z); o0.w = f2bf(v0.w);
    o1.x = f2bf(v1.x); o1.y = f2bf(v1.y); o1.z = f2bf(v1.z); o1.w = f2bf(v1.w);
    *(ushort4*)dst = o0; *(ushort4*)(dst + 4) = o1;
  }
  __syncthreads();

  // pointwise ownership: 2 cells/thread; bias preloaded to registers
  const int pb = (tid * 2) >> 4;               // batch 0..63
  const int pc = (tid * 2) & 15;               // col pair base (even)
  float c_state0 = 0.f, c_state1 = 0.f;
  float bia[4], bib[4];
  #pragma unroll
  for (int g2 = 0; g2 < 4; g2++){
    bia[g2] = bsum[g2 * 1024 + c0 + pc];
    bib[g2] = bsum[g2 * 1024 + c0 + pc + 1];
  }

  const int arow = msub * 32 + lr;             // batch rows for this wave's m-tiles
  // h layout: elem(step,row,k) = step*65536 + (k>>4)*1024 + row*16 + (k&15)
  const int jc = g >> 1;
  const int cc = (g & 1) * 8;
  // xp B-operand: Wih rows (gate*1024 + c0 + lr), same frag pattern as Whh path
  const u16* wibase = Wih_bf + ((size_t)(gate << 10) + c0 + lr) * 1024 + g * 8;

// group gq = k-tiles [gq*4, gq*4+4) = producer blocks [gq*8, gq*8+8)
#define SPING(gq) \
  do { while (lds_ready[gq] < step) __builtin_amdgcn_s_sleep(1); \
       asm volatile("" ::: "memory"); } while (0)

#define LOADG(s0, s1, gq) \
  do { const u16* A0_ = pa0 + (gq) * 8192; const u16* A1_ = pa1 + (gq) * 8192; \
       s0[0] = *(const bf16x8*)(A0_);        s1[0] = *(const bf16x8*)(A1_); \
       s0[1] = *(const bf16x8*)(A0_ + 2048); s1[1] = *(const bf16x8*)(A1_ + 2048); \
       s0[2] = *(const bf16x8*)(A0_ + 4096); s1[2] = *(const bf16x8*)(A1_ + 4096); \
       s0[3] = *(const bf16x8*)(A0_ + 6144); s1[3] = *(const bf16x8*)(A1_ + 6144); } while (0)

#define MFMAG(s0, s1, gq) \
  do { const u16* wb_ = wlds + ((size_t)(gate * 32 + (gq) * 4) * 16 + lr) * 32 + g * 8; \
       bf16x8 b0_ = *(const bf16x8*)(wb_); \
       bf16x8 b1_ = *(const bf16x8*)(wb_ + 512); \
       bf16x8 b2_ = *(const bf16x8*)(wb_ + 1024); \
       bf16x8 b3_ = *(const bf16x8*)(wb_ + 1536); \
       acc0 = MFMA16(s0[0], b0_, acc0); acc1 = MFMA16(s1[0], b0_, acc1); \
       acc0 = MFMA16(s0[1], b1_, acc0); acc1 = MFMA16(s1[1], b1_, acc1); \
       acc0 = MFMA16(s0[2], b2_, acc0); acc1 = MFMA16(s1[2], b2_, acc1); \
       acc0 = MFMA16(s0[3], b3_, acc0); acc1 = MFMA16(s1[3], b3_, acc1); } while (0)

  #pragma unroll 1
  for (int step = 0; step < T_Q; step++){
    // ---- xp slice GEMM: gates_x = x_t * Wih_slice^T (independent work that
    // fills the publish->detect idle; A/B frags L2/L3-served) ----
    f32x4 ax0 = {0,0,0,0}, ax1 = {0,0,0,0};
    {
      const u16* xb0 = x_bf + ((size_t)(step * NB) + arow) * 1024 + g * 8;
      const u16* xb1 = xb0 + (size_t)16 * 1024;
      #pragma unroll 4
      for (int t = 0; t < 32; t++){
        bf16x8 xa = *(const bf16x8*)(xb0 + t * 32);
        bf16x8 xc = *(const bf16x8*)(xb1 + t * 32);
        bf16x8 bw = *(const bf16x8*)(wibase + t * 32);
        ax0 = MFMA16(xa, bw, ax0);
        ax1 = MFMA16(xc, bw, ax1);
      }
    }

    f32x4 acc0 = {0,0,0,0}, acc1 = {0,0,0,0};

    if (step > 0){
      // ---- wave 0: sole global poller; signals per-group readiness via LDS ----
      if (w == 0){
        unsigned done = 0;
        const int* fp = flags + lane * 16;
        while (done != 0xFFu){
          int f = ld_flag(fp);
          unsigned long long b = __ballot(f >= step);
          #pragma unroll
          for (int gq = 0; gq < 8; gq++){
            if (((done >> gq) & 1u) == 0 &&
                ((unsigned)(b >> (gq * 8)) & 0xFFu) == 0xFFu){
              if (lane == 0) lds_ready[gq] = step;
              done |= 1u << gq;
            }
          }
          if (done != 0xFFu) __builtin_amdgcn_s_sleep(1);
        }
      }

      const u16* hb  = hsteps + (size_t)(step - 1) * 65536;
      const u16* pa0 = hb + (size_t)jc * 1024 + (size_t)arow * 16 + cc;
      const u16* pa1 = pa0 + 256;              // rows arow+16

      bf16x8 sA0[4], sA1[4], sB0[4], sB1[4];
      SPING(0); LOADG(sA0, sA1, 0);
      SPING(1); LOADG(sB0, sB1, 1); MFMAG(sA0, sA1, 0);
      SPING(2); LOADG(sA0, sA1, 2); MFMAG(sB0, sB1, 1);
      SPING(3); LOADG(sB0, sB1, 3); MFMAG(sA0, sA1, 2);
      SPING(4); LOADG(sA0, sA1, 4); MFMAG(sB0, sB1, 3);
      SPING(5); LOADG(sB0, sB1, 5); MFMAG(sA0, sA1, 4);
      SPING(6); LOADG(sA0, sA1, 6); MFMAG(sB0, sB1, 5);
      SPING(7); LOADG(sB0, sB1, 7); MFMAG(sA0, sA1, 6);
      MFMAG(sB0, sB1, 7);
    }

    // gl = h-part + x-part. C/D: col=lane&15, row=(lane>>4)*4+reg
    #pragma unroll
    for (int r = 0; r < 4; r++){
      gl[(gate * 64 + msub * 32 +      g * 4 + r) * 16 + lr] = acc0[r] + ax0[r];
      gl[(gate * 64 + msub * 32 + 16 + g * 4 + r) * 16 + lr] = acc1[r] + ax1[r];
    }
    __syncthreads();

    // pointwise: 2 cells (pb, pc) (pb, pc+1); bias from registers
    float hout0, hout1; u16 hb0, hb1;
    {
      float ig = gl[(0 * 64 + pb) * 16 + pc] + bia[0];
      float fg = gl[(1 * 64 + pb) * 16 + pc] + bia[1];
      float gg = gl[(2 * 64 + pb) * 16 + pc] + bia[2];
      float og = gl[(3 * 64 + pb) * 16 + pc] + bia[3];
      float cn = sigm(fg) * c_state0 + sigm(ig) * tanh_f(gg);
      c_state0 = cn;
      hout0 = sigm(og) * tanh_f(cn); hb0 = f2bf(hout0);
    }
    {
      float ig = gl[(0 * 64 + pb) * 16 + pc + 1] + bib[0];
      float fg = gl[(1 * 64 + pb) * 16 + pc + 1] + bib[1];
      float gg = gl[(2 * 64 + pb) * 16 + pc + 1] + bib[2];
      float og = gl[(3 * 64 + pb) * 16 + pc + 1] + bib[3];
      float cn = sigm(fg) * c_state1 + sigm(ig) * tanh_f(gg);
      c_state1 = cn;
      hout1 = sigm(og) * tanh_f(cn); hb1 = f2bf(hout1);
    }

    if (step < T_Q - 1){
      // publish h_step into block-contiguous region, then flag. One dword/thread.
      u16* hw = hsteps + (size_t)step * 65536 + (size_t)blockIdx.x * 1024 + pb * 16 + pc;
      unsigned hpack = (unsigned)hb0 | ((unsigned)hb1 << 16);
      st_b32_cc(hw, hpack);
      asm volatile("s_waitcnt vmcnt(0)" ::: "memory");
      __syncthreads();                          // whole block's h is at L3
      if (tid == 0) st_flag(flags + blockIdx.x * 16, step + 1);
    }

    ushort2 hh; hh.x = hb0; hh.y = hb1;
    *(ushort2*)(qbuf + ((size_t)pb * T_Q + step) * HDIM + c0 + pc) = hh;
    float2 ho; ho.x = hout0; ho.y = hout1;
    *(float2*)(out0 + ((size_t)(step * NB + pb)) * HDIM + c0 + pc) = ho;
  }
#undef SPING
#undef LOADG
#undef MFMAG
}

// ---------------- fused attention: scores -> softmax -> context ----------------
// block per (b,q). wave w handles keys k in [w*12, min(len,w*12+12)). len-bounded.

__global__ __launch_bounds__(256) void attn_fused(
  const float* __restrict__ aq, const u16* __restrict__ ak,
  const float* __restrict__ vhat, const u16* __restrict__ keys,
  const int* __restrict__ lens, float* __restrict__ out1)
{
  int b = blockIdx.x >> 5, q = blockIdx.x & 31;
  int t = threadIdx.x, lane = t & 63, w = t >> 6;
  __shared__ float sc[T_K];
  __shared__ float ps[T_K];
  int len = lens[b];
  float aqr[16], vh[16];
  const float* aqp = aq + (size_t)(b * T_Q + q) * HDIM + lane * 16;
  const float* vp  = vhat + lane * 16;
  #pragma unroll
  for (int j = 0; j < 4; j++){
    float4 v0 = ((const float4*)aqp)[j];
    float4 v1 = ((const float4*)vp)[j];
    aqr[j*4+0] = v0.x; aqr[j*4+1] = v0.y; aqr[j*4+2] = v0.z; aqr[j*4+3] = v0.w;
    vh[j*4+0]  = v1.x; vh[j*4+1]  = v1.y; vh[j*4+2]  = v1.z; vh[j*4+3]  = v1.w;
  }

  int kmax = len - w * 12; if (kmax > 12) kmax = 12;
  for (int kk = 0; kk < kmax; kk++){
    int k = w * 12 + kk;
    const u16* akp = ak + (size_t)(k * NB + b) * HDIM + lane * 16;
    us8 a0 = *(const us8*)(akp);
    us8 a1 = *(const us8*)(akp + 8);
    float p = 0.f;
    #pragma unroll
    for (int j = 0; j < 8; j++){
      p += tanh_f(aqr[j]     + bf2f(a0[j])) * vh[j];
      p += tanh_f(aqr[8 + j] + bf2f(a1[j])) * vh[8 + j];
    }
    #pragma unroll
    for (int m = 32; m >= 1; m >>= 1) p += __shfl_xor(p, m);
    if (lane == 0) sc[k] = p;
  }
  __syncthreads();
  float mx = -3.0e38f;
  for (int k = 0; k < len; k++) mx = fmaxf(mx, sc[k]);
  if (t < len) ps[t] = __expf(sc[t] - mx);
  __syncthreads();
  float den = 0.f;
  for (int k = 0; k < len; k++) den += ps[k];
  float rden = __builtin_amdgcn_rcpf(den);

  float c0 = 0.f, c1 = 0.f, c2 = 0.f, c3 = 0.f;
  for (int k = 0; k < len; k++){
    float pk = ps[k];
    ushort4 kv = *(const ushort4*)(keys + (size_t)(k * NB + b) * HDIM + t * 4);
    c0 += pk * bf2f(kv.x); c1 += pk * bf2f(kv.y);
    c2 += pk * bf2f(kv.z); c3 += pk * bf2f(kv.w);
  }
  size_t o = (size_t)(q * NB + b) * HDIM + t * 4;
  out1[o + 0] = c0 * rden;
  out1[o + 1] = c1 * rden;
  out1[o + 2] = c2 * rden;
  out1[o + 3] = c3 * rden;
}

// ---------------- launch ----------------

extern "C" void kernel_launch(void* const* d_in, const int* in_sizes, int n_in,
                              void* d_out, int out_size, void* d_ws, size_t ws_size,
                              hipStream_t stream)
{
  const float* in1  = (const float*)d_in[0];   // input1
  const float* in0  = (const float*)d_in[1];   // input0
  const int*   lens = (const int*)d_in[2];     // input2
  const int*   toks = (const int*)d_in[3];     // input3
  const float* emb  = (const float*)d_in[4];
  const float* Wih  = (const float*)d_in[5];
  const float* Whh  = (const float*)d_in[6];
  const float* bih  = (const float*)d_in[7];
  const float* bhh  = (const float*)d_in[8];
  const float* Wq   = (const float*)d_in[9];
  const float* Wk   = (const float*)d_in[10];
  const float* vatt = (const float*)d_in[11];
  const float* ns   = (const float*)d_in[12];
  const float* nbb  = (const float*)d_in[13];

  char* p = (char*)d_ws;
  u16* x_bf    = (u16*)p;   p += (size_t)2048 * 1024 * 2;   // 4 MB
  u16* keys_bf = (u16*)p;   p += (size_t)3072 * 1024 * 2;   // 6 MB
  u16* hsteps  = (u16*)p;   p += (size_t)32 * 65536 * 2;    // 4 MB rotating h
  u16* qbuf    = (u16*)p;   p += (size_t)2048 * 1024 * 2;   // 4 MB
  float* aq    = (float*)p; p += (size_t)2048 * 1024 * 4;   // 8 MB
  float* vhat  = (float*)p; p += 1024 * 4;
  float* bsum  = (float*)p; p += 4096 * 4;
  float* nbf   = (float*)p; p += 1024 * 4;
  int* flags   = (int*)p;   p += 4096;                      // 64 flags, 64B apart
  u16* ak      = (u16*)p;   p += (size_t)3072 * 1024 * 2;   // 6 MB
  u16* Wih_bf  = (u16*)p;   p += (size_t)4096 * 1024 * 2;   // 8 MB
  u16* Wq_bf   = (u16*)p;   p += (size_t)1024 * 1024 * 2;   // 2 MB
  u16* Wk_bf   = (u16*)p;   p += (size_t)1024 * 1024 * 2;   // 2 MB

  float* out0 = (float*)d_out;
  float* out1 = out0 + (size_t)T_Q * NB * HDIM;

  hipMemsetAsync(flags, 0, 4096, stream);

  conv_f2b<<<4096, 256, 0, stream>>>(Wih, Wih_bf);
  conv_f2b<<<1024, 256, 0, stream>>>(Wq,  Wq_bf);
  conv_f2b<<<1024, 256, 0, stream>>>(Wk,  Wk_bf);
  gather_x<<<2048, 256, 0, stream>>>(toks, emb, x_bf);
  make_keys<<<3072, 256, 0, stream>>>(in1, in0, keys_bf);
  prep_small<<<1, 256, 0, stream>>>(vatt, ns, nbb, vhat, nbf);
  prep_bsum<<<16, 256, 0, stream>>>(bih, bhh, bsum);

  // ak = keys * Wk^T + norm_bias : M=3072, N=1024, K=1024 -> bf16
  gemm_bf16<1><<<dim3(16, 48), 256, 0, stream>>>(keys_bf, Wk_bf, nbf, ak, 3072, 1024, 1024);

  // all 32 LSTM steps + fused per-step xp GEMM (144KB+32B dynamic LDS, 1 block/CU)
  lstm_persistent<<<LSTM_BLOCKS, 512, 147488, stream>>>(Whh, x_bf, Wih_bf, bsum,
                                                        hsteps, qbuf, out0, flags);

  // aq = q * Wq^T : M=2048, N=1024, K=1024 -> f32
  gemm_bf16<0><<<dim3(16, 32), 256, 0, stream>>>(qbuf, Wq_bf, nullptr, aq, 2048, 1024, 1024);

  attn_fused<<<2048, 256, 0, stream>>>(aq, ak, vhat, keys_bf, lens, out1);
}

// Round 14
// 940.698 us; speedup vs baseline: 1.0018x; 1.0018x over previous
//
#include <hip/hip_runtime.h>
#include <hip/hip_bf16.h>

typedef unsigned short u16;
typedef __attribute__((ext_vector_type(8))) short bf16x8;
typedef __attribute__((ext_vector_type(8))) unsigned short us8;
typedef __attribute__((ext_vector_type(4))) float f32x4;

#define T_Q 32
#define T_K 48
#define NB 64
#define HDIM 1024
#define MASK_FILL -65504.0f
#define LSTM_BLOCKS 64

__device__ __forceinline__ float bf2f(u16 v){
  union { unsigned u; float f; } x; x.u = ((unsigned)v) << 16; return x.f;
}
__device__ __forceinline__ u16 f2bf(float f){
  union { float f; unsigned u; } x; x.f = f;
  return (u16)((x.u + 0x7FFFu + ((x.u >> 16) & 1u)) >> 16);
}
__device__ __forceinline__ float sigm(float x){
  return __builtin_amdgcn_rcpf(1.f + __expf(-x));
}
__device__ __forceinline__ float tanh_f(float x){
  float e = __expf(2.f * x);
  return fmaf(-2.f, __builtin_amdgcn_rcpf(e + 1.f), 1.f);  // graceful at +/-inf
}

// Cross-XCD coherent sync-path ops (sc0 = bypass L0/L1, sc1 = bypass local L2;
// coherence point = Infinity Cache). Used ONLY for the tiny publish/flag path.
// h DATA loads are normal cached loads against write-once rotating buffers (r6).
// r7 lesson: one global poller per block. r10: wave-specialized staging regressed.
// r11: gemm128 loses to gemm64 here (TLP). r12: dual-chain regressed (2x sync).
// r13: fill the publish->detect idle with INDEPENDENT work (xp GEMM) instead.
__device__ __forceinline__ void st_b32_cc(u16* a, unsigned v){
  asm volatile("global_store_dword %0, %1, off sc0 sc1" :: "v"(a), "v"(v) : "memory");
}
__device__ __forceinline__ void st_flag(int* a, int v){
  asm volatile("global_store_dword %0, %1, off sc0 sc1" :: "v"(a), "v"(v) : "memory");
}
__device__ __forceinline__ int ld_flag(const int* a){
  int r;
  asm volatile("global_load_dword %0, %1, off sc0 sc1\n\ts_waitcnt vmcnt(0)"
               : "=v"(r) : "v"(a) : "memory");
  return r;
}

#define MFMA16(A,B,C) __builtin_amdgcn_mfma_f32_16x16x32_bf16(A,B,C,0,0,0)

// ---------------- prep kernels ----------------

__global__ void conv_f2b(const float* __restrict__ s, u16* __restrict__ d){
  size_t i = ((size_t)blockIdx.x * 256 + threadIdx.x) * 4;
  float4 v = *(const float4*)(s + i);
  ushort4 o; o.x = f2bf(v.x); o.y = f2bf(v.y); o.z = f2bf(v.z); o.w = f2bf(v.w);
  *(ushort4*)(d + i) = o;
}

__global__ void gather_x(const int* __restrict__ tok, const float* __restrict__ emb,
                         u16* __restrict__ x){
  int r = blockIdx.x;                      // r = t*64 + b
  int token = tok[r];
  float4 v = ((const float4*)(emb + (size_t)token * HDIM))[threadIdx.x];
  ushort4 o; o.x = f2bf(v.x); o.y = f2bf(v.y); o.z = f2bf(v.z); o.w = f2bf(v.w);
  ((ushort4*)(x + (size_t)r * HDIM))[threadIdx.x] = o;
}

__global__ void make_keys(const float* __restrict__ a, const float* __restrict__ b,
                          u16* __restrict__ o){
  size_t i = ((size_t)blockIdx.x * 256 + threadIdx.x) * 4;
  float4 va = *(const float4*)(a + i);
  float4 vb = *(const float4*)(b + i);
  ushort4 vo;
  vo.x = f2bf(va.x + vb.x);
  vo.y = f2bf(va.y + vb.y);
  vo.z = f2bf(va.z + vb.z);
  vo.w = f2bf(va.w + vb.w);
  *(ushort4*)(o + i) = vo;
}

__global__ void prep_small(const float* __restrict__ vatt, const float* __restrict__ ns,
                           const float* __restrict__ nb,
                           float* __restrict__ vhat, float* __restrict__ nbias){
  __shared__ float wred[4];
  int t = threadIdx.x, lane = t & 63, w = t >> 6;
  float vv[4]; float s = 0.f;
  #pragma unroll
  for (int j = 0; j < 4; j++){ vv[j] = vatt[t*4 + j]; s += vv[j]*vv[j]; }
  #pragma unroll
  for (int m = 32; m >= 1; m >>= 1) s += __shfl_xor(s, m);
  if (lane == 0) wred[w] = s;
  __syncthreads();
  float tot = wred[0] + wred[1] + wred[2] + wred[3];
  float scale = ns[0] / sqrtf(tot);
  #pragma unroll
  for (int j = 0; j < 4; j++) vhat[t*4 + j] = vv[j] * scale;
  #pragma unroll
  for (int j = 0; j < 4; j++){ int i = t + 256*j; nbias[i] = nb[i]; }
}

__global__ void prep_bsum(const float* __restrict__ bih, const float* __restrict__ bhh,
                          float* __restrict__ bias_sum){
  int i = blockIdx.x * 256 + threadIdx.x;
  bias_sum[i] = bih[i] + bhh[i];
}

// ---------------- generic bf16 GEMM (r6/r9-proven 64x64 tile) ----------------
// C[M][N] = A[M][K] * W[N][K]^T + bias. OB=1 -> bf16 out, OB=0 -> f32 out.

template<int OB>
__global__ __launch_bounds__(256) void gemm_bf16(
  const u16* __restrict__ A, const u16* __restrict__ W,
  const float* __restrict__ bias, void* __restrict__ Cv,
  int M, int N, int K)
{
  __shared__ __align__(16) u16 As[4][66][8];   // [kc][row][8], kc-stride 1056B
  __shared__ __align__(16) u16 Bs[4][66][8];
  const int t = threadIdx.x;
  const int m0 = blockIdx.y * 64, n0 = blockIdx.x * 64;
  const int lane = t & 63, w = t >> 6;
  const int wm = (w >> 1) * 32, wn = (w & 1) * 32;
  const int lr = lane & 15, g = lane >> 4;
  const int lrow = t >> 2, lkc = t & 3;
  f32x4 acc00 = {0,0,0,0}, acc01 = {0,0,0,0}, acc10 = {0,0,0,0}, acc11 = {0,0,0,0};
  const u16* aptr = A + (size_t)(m0 + lrow) * K + lkc * 8;
  const u16* wptr = W + (size_t)(n0 + lrow) * K + lkc * 8;
  for (int k0 = 0; k0 < K; k0 += 32){
    *(bf16x8*)(&As[lkc][lrow][0]) = *(const bf16x8*)(aptr + k0);
    *(bf16x8*)(&Bs[lkc][lrow][0]) = *(const bf16x8*)(wptr + k0);
    __syncthreads();
    bf16x8 a0 = *(const bf16x8*)(&As[g][wm      + lr][0]);
    bf16x8 a1 = *(const bf16x8*)(&As[g][wm + 16 + lr][0]);
    bf16x8 b0 = *(const bf16x8*)(&Bs[g][wn      + lr][0]);
    bf16x8 b1 = *(const bf16x8*)(&Bs[g][wn + 16 + lr][0]);
    acc00 = MFMA16(a0, b0, acc00);
    acc01 = MFMA16(a0, b1, acc01);
    acc10 = MFMA16(a1, b0, acc10);
    acc11 = MFMA16(a1, b1, acc11);
    __syncthreads();
  }
  // C/D layout: col = lane&15, row = (lane>>4)*4 + reg   [m89-verified]
  const int rb = m0 + wm + g * 4;
  const int cb = n0 + wn + lr;
  float bv0 = bias ? bias[cb]      : 0.f;
  float bv1 = bias ? bias[cb + 16] : 0.f;
  #pragma unroll
  for (int r = 0; r < 4; r++){
    float v00 = acc00[r] + bv0, v01 = acc01[r] + bv1;
    float v10 = acc10[r] + bv0, v11 = acc11[r] + bv1;
    if (OB){
      u16* C = (u16*)Cv;
      C[(size_t)(rb + r)      * N + cb]      = f2bf(v00);
      C[(size_t)(rb + r)      * N + cb + 16] = f2bf(v01);
      C[(size_t)(rb + 16 + r) * N + cb]      = f2bf(v10);
      C[(size_t)(rb + 16 + r) * N + cb + 16] = f2bf(v11);
    } else {
      float* C = (float*)Cv;
      C[(size_t)(rb + r)      * N + cb]      = v00;
      C[(size_t)(rb + r)      * N + cb + 16] = v01;
      C[(size_t)(rb + 16 + r) * N + cb]      = v10;
      C[(size_t)(rb + 16 + r) * N + cb + 16] = v11;
    }
  }
}

// ---------------- persistent LSTM (r13: fused xp GEMM in the idle window) ----------------
// r9 structure verbatim (best measured: 201us) PLUS: each step first computes its
// own xp slice gates_x = x_t * Wih_slice^T (no recurrence dependence!) BEFORE the
// flag poll -- this work fills the publish->L3->detect window that was ~80% stall
// (MfmaUtil 3.2%). Eliminates the standalone 57us xp GEMM and its 16MB buffer.
// xp fragment patterns identical to the verified h*Whh^T path; bias (bsum) moves
// to 8 preloaded registers in the pointwise; gl = acc_h + acc_x.

__global__ __launch_bounds__(512, 1) void lstm_persistent(
  const float* __restrict__ Whh, const u16* __restrict__ x_bf,
  const u16* __restrict__ Wih_bf, const float* __restrict__ bsum,
  u16* __restrict__ hsteps,
  u16* __restrict__ qbuf, float* __restrict__ out0,
  int* __restrict__ flags)
{
  extern __shared__ char smem[];
  u16*  wlds = (u16*)smem;                    // [4][32][16][32] bf16 (128KB)
  float* gl  = (float*)(smem + 131072);       // [4][64][16] f32 (16KB)
  volatile int* lds_ready = (volatile int*)(smem + 147456);  // [8]

  const int tid = threadIdx.x;
  const int c0 = blockIdx.x * 16;
  const int lane = tid & 63, w = tid >> 6;    // 8 waves
  const int gate = w & 3, msub = w >> 2;      // wave -> (gate, m-half)
  const int lr = lane & 15, g = lane >> 4;

  if (tid < 8) lds_ready[tid] = 0;

  // ---- one-time: Whh slice f32 -> bf16 -> LDS ----
  #pragma unroll
  for (int i = 0; i < 16; i++){
    int e = (i * 512 + tid) * 8;               // element in 64x1024 slice
    int R = e >> 10, k = e & 1023;
    int gg = R >> 4, rr = R & 15, tt = k >> 5, kk = k & 31;
    const float* src = Whh + (size_t)((gg << 10) + c0 + rr) * 1024 + k;
    float4 v0 = *(const float4*)(src);
    float4 v1 = *(const float4*)(src + 4);
    u16* dst = wlds + (((gg * 32 + tt) * 16 + rr) * 32 + kk);
    ushort4 o0, o1;
    o0.x = f2bf(v0.x); o0.y = f2bf(v0.y); o0.z = f2bf(v0.z); o0.w = f2bf(v0.w);
    o1.x = f2bf(v1.x); o1.y = f2bf(v1.y); o1.z = f2bf(v1.z); o1.w = f2bf(v1.w);
    *(ushort4*)dst = o0; *(ushort4*)(dst + 4) = o1;
  }
  __syncthreads();

  // pointwise ownership: 2 cells/thread; bias preloaded to registers
  const int pb = (tid * 2) >> 4;               // batch 0..63
  const int pc = (tid * 2) & 15;               // col pair base (even)
  float c_state0 = 0.f, c_state1 = 0.f;
  float bia[4], bib[4];
  #pragma unroll
  for (int g2 = 0; g2 < 4; g2++){
    bia[g2] = bsum[g2 * 1024 + c0 + pc];
    bib[g2] = bsum[g2 * 1024 + c0 + pc + 1];
  }

  const int arow = msub * 32 + lr;             // batch rows for this wave's m-tiles
  // h layout: elem(step,row,k) = step*65536 + (k>>4)*1024 + row*16 + (k&15)
  const int jc = g >> 1;
  const int cc = (g & 1) * 8;
  // xp B-operand: Wih rows (gate*1024 + c0 + lr), same frag pattern as Whh path
  const u16* wibase = Wih_bf + ((size_t)(gate << 10) + c0 + lr) * 1024 + g * 8;

// group gq = k-tiles [gq*4, gq*4+4) = producer blocks [gq*8, gq*8+8)
#define SPING(gq) \
  do { while (lds_ready[gq] < step) __builtin_amdgcn_s_sleep(1); \
       asm volatile("" ::: "memory"); } while (0)

#define LOADG(s0, s1, gq) \
  do { const u16* A0_ = pa0 + (gq) * 8192; const u16* A1_ = pa1 + (gq) * 8192; \
       s0[0] = *(const bf16x8*)(A0_);        s1[0] = *(const bf16x8*)(A1_); \
       s0[1] = *(const bf16x8*)(A0_ + 2048); s1[1] = *(const bf16x8*)(A1_ + 2048); \
       s0[2] = *(const bf16x8*)(A0_ + 4096); s1[2] = *(const bf16x8*)(A1_ + 4096); \
       s0[3] = *(const bf16x8*)(A0_ + 6144); s1[3] = *(const bf16x8*)(A1_ + 6144); } while (0)

#define MFMAG(s0, s1, gq) \
  do { const u16* wb_ = wlds + ((size_t)(gate * 32 + (gq) * 4) * 16 + lr) * 32 + g * 8; \
       bf16x8 b0_ = *(const bf16x8*)(wb_); \
       bf16x8 b1_ = *(const bf16x8*)(wb_ + 512); \
       bf16x8 b2_ = *(const bf16x8*)(wb_ + 1024); \
       bf16x8 b3_ = *(const bf16x8*)(wb_ + 1536); \
       acc0 = MFMA16(s0[0], b0_, acc0); acc1 = MFMA16(s1[0], b0_, acc1); \
       acc0 = MFMA16(s0[1], b1_, acc0); acc1 = MFMA16(s1[1], b1_, acc1); \
       acc0 = MFMA16(s0[2], b2_, acc0); acc1 = MFMA16(s1[2], b2_, acc1); \
       acc0 = MFMA16(s0[3], b3_, acc0); acc1 = MFMA16(s1[3], b3_, acc1); } while (0)

  #pragma unroll 1
  for (int step = 0; step < T_Q; step++){
    // ---- xp slice GEMM: gates_x = x_t * Wih_slice^T (independent work that
    // fills the publish->detect idle; A/B frags L2/L3-served) ----
    f32x4 ax0 = {0,0,0,0}, ax1 = {0,0,0,0};
    {
      const u16* xb0 = x_bf + ((size_t)(step * NB) + arow) * 1024 + g * 8;
      const u16* xb1 = xb0 + (size_t)16 * 1024;
      #pragma unroll 4
      for (int t = 0; t < 32; t++){
        bf16x8 xa = *(const bf16x8*)(xb0 + t * 32);
        bf16x8 xc = *(const bf16x8*)(xb1 + t * 32);
        bf16x8 bw = *(const bf16x8*)(wibase + t * 32);
        ax0 = MFMA16(xa, bw, ax0);
        ax1 = MFMA16(xc, bw, ax1);
      }
    }

    f32x4 acc0 = {0,0,0,0}, acc1 = {0,0,0,0};

    if (step > 0){
      // ---- wave 0: sole global poller; signals per-group readiness via LDS ----
      if (w == 0){
        unsigned done = 0;
        const int* fp = flags + lane * 16;
        while (done != 0xFFu){
          int f = ld_flag(fp);
          unsigned long long b = __ballot(f >= step);
          #pragma unroll
          for (int gq = 0; gq < 8; gq++){
            if (((done >> gq) & 1u) == 0 &&
                ((unsigned)(b >> (gq * 8)) & 0xFFu) == 0xFFu){
              if (lane == 0) lds_ready[gq] = step;
              done |= 1u << gq;
            }
          }
          if (done != 0xFFu) __builtin_amdgcn_s_sleep(1);
        }
      }

      const u16* hb  = hsteps + (size_t)(step - 1) * 65536;
      const u16* pa0 = hb + (size_t)jc * 1024 + (size_t)arow * 16 + cc;
      const u16* pa1 = pa0 + 256;              // rows arow+16

      bf16x8 sA0[4], sA1[4], sB0[4], sB1[4];
      SPING(0); LOADG(sA0, sA1, 0);
      SPING(1); LOADG(sB0, sB1, 1); MFMAG(sA0, sA1, 0);
      SPING(2); LOADG(sA0, sA1, 2); MFMAG(sB0, sB1, 1);
      SPING(3); LOADG(sB0, sB1, 3); MFMAG(sA0, sA1, 2);
      SPING(4); LOADG(sA0, sA1, 4); MFMAG(sB0, sB1, 3);
      SPING(5); LOADG(sB0, sB1, 5); MFMAG(sA0, sA1, 4);
      SPING(6); LOADG(sA0, sA1, 6); MFMAG(sB0, sB1, 5);
      SPING(7); LOADG(sB0, sB1, 7); MFMAG(sA0, sA1, 6);
      MFMAG(sB0, sB1, 7);
    }

    // gl = h-part + x-part. C/D: col=lane&15, row=(lane>>4)*4+reg
    #pragma unroll
    for (int r = 0; r < 4; r++){
      gl[(gate * 64 + msub * 32 +      g * 4 + r) * 16 + lr] = acc0[r] + ax0[r];
      gl[(gate * 64 + msub * 32 + 16 + g * 4 + r) * 16 + lr] = acc1[r] + ax1[r];
    }
    __syncthreads();

    // pointwise: 2 cells (pb, pc) (pb, pc+1); bias from registers
    float hout0, hout1; u16 hb0, hb1;
    {
      float ig = gl[(0 * 64 + pb) * 16 + pc] + bia[0];
      float fg = gl[(1 * 64 + pb) * 16 + pc] + bia[1];
      float gg = gl[(2 * 64 + pb) * 16 + pc] + bia[2];
      float og = gl[(3 * 64 + pb) * 16 + pc] + bia[3];
      float cn = sigm(fg) * c_state0 + sigm(ig) * tanh_f(gg);
      c_state0 = cn;
      hout0 = sigm(og) * tanh_f(cn); hb0 = f2bf(hout0);
    }
    {
      float ig = gl[(0 * 64 + pb) * 16 + pc + 1] + bib[0];
      float fg = gl[(1 * 64 + pb) * 16 + pc + 1] + bib[1];
      float gg = gl[(2 * 64 + pb) * 16 + pc + 1] + bib[2];
      float og = gl[(3 * 64 + pb) * 16 + pc + 1] + bib[3];
      float cn = sigm(fg) * c_state1 + sigm(ig) * tanh_f(gg);
      c_state1 = cn;
      hout1 = sigm(og) * tanh_f(cn); hb1 = f2bf(hout1);
    }

    if (step < T_Q - 1){
      // publish h_step into block-contiguous region, then flag. One dword/thread.
      u16* hw = hsteps + (size_t)step * 65536 + (size_t)blockIdx.x * 1024 + pb * 16 + pc;
      unsigned hpack = (unsigned)hb0 | ((unsigned)hb1 << 16);
      st_b32_cc(hw, hpack);
      asm volatile("s_waitcnt vmcnt(0)" ::: "memory");
      __syncthreads();                          // whole block's h is at L3
      if (tid == 0) st_flag(flags + blockIdx.x * 16, step + 1);
    }

    ushort2 hh; hh.x = hb0; hh.y = hb1;
    *(ushort2*)(qbuf + ((size_t)pb * T_Q + step) * HDIM + c0 + pc) = hh;
    float2 ho; ho.x = hout0; ho.y = hout1;
    *(float2*)(out0 + ((size_t)(step * NB + pb)) * HDIM + c0 + pc) = ho;
  }
#undef SPING
#undef LOADG
#undef MFMAG
}

// ---------------- fused attention: scores -> softmax -> context ----------------
// block per (b,q). wave w handles keys k in [w*12, min(len,w*12+12)). len-bounded.

__global__ __launch_bounds__(256) void attn_fused(
  const float* __restrict__ aq, const u16* __restrict__ ak,
  const float* __restrict__ vhat, const u16* __restrict__ keys,
  const int* __restrict__ lens, float* __restrict__ out1)
{
  int b = blockIdx.x >> 5, q = blockIdx.x & 31;
  int t = threadIdx.x, lane = t & 63, w = t >> 6;
  __shared__ float sc[T_K];
  __shared__ float ps[T_K];
  int len = lens[b];
  float aqr[16], vh[16];
  const float* aqp = aq + (size_t)(b * T_Q + q) * HDIM + lane * 16;
  const float* vp  = vhat + lane * 16;
  #pragma unroll
  for (int j = 0; j < 4; j++){
    float4 v0 = ((const float4*)aqp)[j];
    float4 v1 = ((const float4*)vp)[j];
    aqr[j*4+0] = v0.x; aqr[j*4+1] = v0.y; aqr[j*4+2] = v0.z; aqr[j*4+3] = v0.w;
    vh[j*4+0]  = v1.x; vh[j*4+1]  = v1.y; vh[j*4+2]  = v1.z; vh[j*4+3]  = v1.w;
  }

  int kmax = len - w * 12; if (kmax > 12) kmax = 12;
  for (int kk = 0; kk < kmax; kk++){
    int k = w * 12 + kk;
    const u16* akp = ak + (size_t)(k * NB + b) * HDIM + lane * 16;
    us8 a0 = *(const us8*)(akp);
    us8 a1 = *(const us8*)(akp + 8);
    float p = 0.f;
    #pragma unroll
    for (int j = 0; j < 8; j++){
      p += tanh_f(aqr[j]     + bf2f(a0[j])) * vh[j];
      p += tanh_f(aqr[8 + j] + bf2f(a1[j])) * vh[8 + j];
    }
    #pragma unroll
    for (int m = 32; m >= 1; m >>= 1) p += __shfl_xor(p, m);
    if (lane == 0) sc[k] = p;
  }
  __syncthreads();
  float mx = -3.0e38f;
  for (int k = 0; k < len; k++) mx = fmaxf(mx, sc[k]);
  if (t < len) ps[t] = __expf(sc[t] - mx);
  __syncthreads();
  float den = 0.f;
  for (int k = 0; k < len; k++) den += ps[k];
  float rden = __builtin_amdgcn_rcpf(den);

  float c0 = 0.f, c1 = 0.f, c2 = 0.f, c3 = 0.f;
  for (int k = 0; k < len; k++){
    float pk = ps[k];
    ushort4 kv = *(const ushort4*)(keys + (size_t)(k * NB + b) * HDIM + t * 4);
    c0 += pk * bf2f(kv.x); c1 += pk * bf2f(kv.y);
    c2 += pk * bf2f(kv.z); c3 += pk * bf2f(kv.w);
  }
  size_t o = (size_t)(q * NB + b) * HDIM + t * 4;
  out1[o + 0] = c0 * rden;
  out1[o + 1] = c1 * rden;
  out1[o + 2] = c2 * rden;
  out1[o + 3] = c3 * rden;
}

// ---------------- launch ----------------

extern "C" void kernel_launch(void* const* d_in, const int* in_sizes, int n_in,
                              void* d_out, int out_size, void* d_ws, size_t ws_size,
                              hipStream_t stream)
{
  const float* in1  = (const float*)d_in[0];   // input1
  const float* in0  = (const float*)d_in[1];   // input0
  const int*   lens = (const int*)d_in[2];     // input2
  const int*   toks = (const int*)d_in[3];     // input3
  const float* emb  = (const float*)d_in[4];
  const float* Wih  = (const float*)d_in[5];
  const float* Whh  = (const float*)d_in[6];
  const float* bih  = (const float*)d_in[7];
  const float* bhh  = (const float*)d_in[8];
  const float* Wq   = (const float*)d_in[9];
  const float* Wk   = (const float*)d_in[10];
  const float* vatt = (const float*)d_in[11];
  const float* ns   = (const float*)d_in[12];
  const float* nbb  = (const float*)d_in[13];

  char* p = (char*)d_ws;
  u16* x_bf    = (u16*)p;   p += (size_t)2048 * 1024 * 2;   // 4 MB
  u16* keys_bf = (u16*)p;   p += (size_t)3072 * 1024 * 2;   // 6 MB
  u16* hsteps  = (u16*)p;   p += (size_t)32 * 65536 * 2;    // 4 MB rotating h
  u16* qbuf    = (u16*)p;   p += (size_t)2048 * 1024 * 2;   // 4 MB
  float* aq    = (float*)p; p += (size_t)2048 * 1024 * 4;   // 8 MB
  float* vhat  = (float*)p; p += 1024 * 4;
  float* bsum  = (float*)p; p += 4096 * 4;
  float* nbf   = (float*)p; p += 1024 * 4;
  int* flags   = (int*)p;   p += 4096;                      // 64 flags, 64B apart
  u16* ak      = (u16*)p;   p += (size_t)3072 * 1024 * 2;   // 6 MB
  u16* Wih_bf  = (u16*)p;   p += (size_t)4096 * 1024 * 2;   // 8 MB
  u16* Wq_bf   = (u16*)p;   p += (size_t)1024 * 1024 * 2;   // 2 MB
  u16* Wk_bf   = (u16*)p;   p += (size_t)1024 * 1024 * 2;   // 2 MB

  float* out0 = (float*)d_out;
  float* out1 = out0 + (size_t)T_Q * NB * HDIM;

  hipMemsetAsync(flags, 0, 4096, stream);

  conv_f2b<<<4096, 256, 0, stream>>>(Wih, Wih_bf);
  conv_f2b<<<1024, 256, 0, stream>>>(Wq,  Wq_bf);
  conv_f2b<<<1024, 256, 0, stream>>>(Wk,  Wk_bf);
  gather_x<<<2048, 256, 0, stream>>>(toks, emb, x_bf);
  make_keys<<<3072, 256, 0, stream>>>(in1, in0, keys_bf);
  prep_small<<<1, 256, 0, stream>>>(vatt, ns, nbb, vhat, nbf);
  prep_bsum<<<16, 256, 0, stream>>>(bih, bhh, bsum);

  // ak = keys * Wk^T + norm_bias : M=3072, N=1024, K=1024 -> bf16
  gemm_bf16<1><<<dim3(16, 48), 256, 0, stream>>>(keys_bf, Wk_bf, nbf, ak, 3072, 1024, 1024);

  // all 32 LSTM steps + fused per-step xp GEMM (144KB+32B dynamic LDS, 1 block/CU)
  lstm_persistent<<<LSTM_BLOCKS, 512, 147488, stream>>>(Whh, x_bf, Wih_bf, bsum,
                                                        hsteps, qbuf, out0, flags);

  // aq = q * Wq^T : M=2048, N=1024, K=1024 -> f32
  gemm_bf16<0><<<dim3(16, 32), 256, 0, stream>>>(qbuf, Wq_bf, nullptr, aq, 2048, 1024, 1024);

  attn_fused<<<2048, 256, 0, stream>>>(aq, ak, vhat, keys_bf, lens, out1);
}

// Round 15
// 557.899 us; speedup vs baseline: 1.6891x; 1.6861x over previous
//
#include <hip/hip_runtime.h>
#include <hip/hip_bf16.h>

typedef unsigned short u16;
typedef __attribute__((ext_vector_type(8))) short bf16x8;
typedef __attribute__((ext_vector_type(8))) unsigned short us8;
typedef __attribute__((ext_vector_type(4))) float f32x4;

#define T_Q 32
#define T_K 48
#define NB 64
#define HDIM 1024
#define MASK_FILL -65504.0f
#define LSTM_BLOCKS 64

__device__ __forceinline__ float bf2f(u16 v){
  union { unsigned u; float f; } x; x.u = ((unsigned)v) << 16; return x.f;
}
__device__ __forceinline__ u16 f2bf(float f){
  union { float f; unsigned u; } x; x.f = f;
  return (u16)((x.u + 0x7FFFu + ((x.u >> 16) & 1u)) >> 16);
}
__device__ __forceinline__ float sigm(float x){
  return __builtin_amdgcn_rcpf(1.f + __expf(-x));
}
__device__ __forceinline__ float tanh_f(float x){
  float e = __expf(2.f * x);
  return fmaf(-2.f, __builtin_amdgcn_rcpf(e + 1.f), 1.f);  // graceful at +/-inf
}

// Cross-XCD coherent publish path (sc0 bypass L0/L1, sc1 bypass local L2;
// coherence point = Infinity Cache). r7: one global poller per wave-set.
// r13/r14 lesson: NEVER put unstaged global-streaming work on the lstm blocks'
// critical path -- use SEPARATE co-launched blocks on the idle CUs instead.
__device__ __forceinline__ void st_b32_cc(u16* a, unsigned v){
  asm volatile("global_store_dword %0, %1, off sc0 sc1" :: "v"(a), "v"(v) : "memory");
}
__device__ __forceinline__ void st_b16_cc(u16* a, u16 v){
  unsigned vv = v;
  asm volatile("global_store_short %0, %1, off sc0 sc1" :: "v"(a), "v"(vv) : "memory");
}
__device__ __forceinline__ void st_flag(int* a, int v){
  asm volatile("global_store_dword %0, %1, off sc0 sc1" :: "v"(a), "v"(v) : "memory");
}
__device__ __forceinline__ int ld_flag(const int* a){
  int r;
  asm volatile("global_load_dword %0, %1, off sc0 sc1\n\ts_waitcnt vmcnt(0)"
               : "=v"(r) : "v"(a) : "memory");
  return r;
}

#define MFMA16(A,B,C) __builtin_amdgcn_mfma_f32_16x16x32_bf16(A,B,C,0,0,0)

// ---------------- prep kernels ----------------

__global__ void conv_f2b(const float* __restrict__ s, u16* __restrict__ d){
  size_t i = ((size_t)blockIdx.x * 256 + threadIdx.x) * 4;
  float4 v = *(const float4*)(s + i);
  ushort4 o; o.x = f2bf(v.x); o.y = f2bf(v.y); o.z = f2bf(v.z); o.w = f2bf(v.w);
  *(ushort4*)(d + i) = o;
}

__global__ void gather_x(const int* __restrict__ tok, const float* __restrict__ emb,
                         u16* __restrict__ x){
  int r = blockIdx.x;                      // r = t*64 + b
  int token = tok[r];
  float4 v = ((const float4*)(emb + (size_t)token * HDIM))[threadIdx.x];
  ushort4 o; o.x = f2bf(v.x); o.y = f2bf(v.y); o.z = f2bf(v.z); o.w = f2bf(v.w);
  ((ushort4*)(x + (size_t)r * HDIM))[threadIdx.x] = o;
}

__global__ void make_keys(const float* __restrict__ a, const float* __restrict__ b,
                          u16* __restrict__ o){
  size_t i = ((size_t)blockIdx.x * 256 + threadIdx.x) * 4;
  float4 va = *(const float4*)(a + i);
  float4 vb = *(const float4*)(b + i);
  ushort4 vo;
  vo.x = f2bf(va.x + vb.x);
  vo.y = f2bf(va.y + vb.y);
  vo.z = f2bf(va.z + vb.z);
  vo.w = f2bf(va.w + vb.w);
  *(ushort4*)(o + i) = vo;
}

__global__ void prep_small(const float* __restrict__ vatt, const float* __restrict__ ns,
                           const float* __restrict__ nb,
                           float* __restrict__ vhat, float* __restrict__ nbias){
  __shared__ float wred[4];
  int t = threadIdx.x, lane = t & 63, w = t >> 6;
  float vv[4]; float s = 0.f;
  #pragma unroll
  for (int j = 0; j < 4; j++){ vv[j] = vatt[t*4 + j]; s += vv[j]*vv[j]; }
  #pragma unroll
  for (int m = 32; m >= 1; m >>= 1) s += __shfl_xor(s, m);
  if (lane == 0) wred[w] = s;
  __syncthreads();
  float tot = wred[0] + wred[1] + wred[2] + wred[3];
  float scale = ns[0] / sqrtf(tot);
  #pragma unroll
  for (int j = 0; j < 4; j++) vhat[t*4 + j] = vv[j] * scale;
  #pragma unroll
  for (int j = 0; j < 4; j++){ int i = t + 256*j; nbias[i] = nb[i]; }
}

__global__ void prep_bsum(const float* __restrict__ bih, const float* __restrict__ bhh,
                          float* __restrict__ bias_sum){
  int i = blockIdx.x * 256 + threadIdx.x;
  bias_sum[i] = bih[i] + bhh[i];
}

// ---------------- generic bf16 GEMM (r6/r9-proven 64x64 tile) ----------------
// C[M][N] = A[M][K] * W[N][K]^T + bias. OB=1 -> bf16 out, OB=0 -> f32 out.

template<int OB>
__global__ __launch_bounds__(256) void gemm_bf16(
  const u16* __restrict__ A, const u16* __restrict__ W,
  const float* __restrict__ bias, void* __restrict__ Cv,
  int M, int N, int K)
{
  __shared__ __align__(16) u16 As[4][66][8];   // [kc][row][8], kc-stride 1056B
  __shared__ __align__(16) u16 Bs[4][66][8];
  const int t = threadIdx.x;
  const int m0 = blockIdx.y * 64, n0 = blockIdx.x * 64;
  const int lane = t & 63, w = t >> 6;
  const int wm = (w >> 1) * 32, wn = (w & 1) * 32;
  const int lr = lane & 15, g = lane >> 4;
  const int lrow = t >> 2, lkc = t & 3;
  f32x4 acc00 = {0,0,0,0}, acc01 = {0,0,0,0}, acc10 = {0,0,0,0}, acc11 = {0,0,0,0};
  const u16* aptr = A + (size_t)(m0 + lrow) * K + lkc * 8;
  const u16* wptr = W + (size_t)(n0 + lrow) * K + lkc * 8;
  for (int k0 = 0; k0 < K; k0 += 32){
    *(bf16x8*)(&As[lkc][lrow][0]) = *(const bf16x8*)(aptr + k0);
    *(bf16x8*)(&Bs[lkc][lrow][0]) = *(const bf16x8*)(wptr + k0);
    __syncthreads();
    bf16x8 a0 = *(const bf16x8*)(&As[g][wm      + lr][0]);
    bf16x8 a1 = *(const bf16x8*)(&As[g][wm + 16 + lr][0]);
    bf16x8 b0 = *(const bf16x8*)(&Bs[g][wn      + lr][0]);
    bf16x8 b1 = *(const bf16x8*)(&Bs[g][wn + 16 + lr][0]);
    acc00 = MFMA16(a0, b0, acc00);
    acc01 = MFMA16(a0, b1, acc01);
    acc10 = MFMA16(a1, b0, acc10);
    acc11 = MFMA16(a1, b1, acc11);
    __syncthreads();
  }
  // C/D layout: col = lane&15, row = (lane>>4)*4 + reg   [m89-verified]
  const int rb = m0 + wm + g * 4;
  const int cb = n0 + wn + lr;
  float bv0 = bias ? bias[cb]      : 0.f;
  float bv1 = bias ? bias[cb + 16] : 0.f;
  #pragma unroll
  for (int r = 0; r < 4; r++){
    float v00 = acc00[r] + bv0, v01 = acc01[r] + bv1;
    float v10 = acc10[r] + bv0, v11 = acc11[r] + bv1;
    if (OB){
      u16* C = (u16*)Cv;
      C[(size_t)(rb + r)      * N + cb]      = f2bf(v00);
      C[(size_t)(rb + r)      * N + cb + 16] = f2bf(v01);
      C[(size_t)(rb + 16 + r) * N + cb]      = f2bf(v10);
      C[(size_t)(rb + 16 + r) * N + cb + 16] = f2bf(v11);
    } else {
      float* C = (float*)Cv;
      C[(size_t)(rb + r)      * N + cb]      = v00;
      C[(size_t)(rb + r)      * N + cb + 16] = v01;
      C[(size_t)(rb + 16 + r) * N + cb]      = v10;
      C[(size_t)(rb + 16 + r) * N + cb + 16] = v11;
    }
  }
}

// ---- shared device helper: load 64 contiguous f32 W rows [row0,row0+64) -> wlds ----
// wlds layout (lstm-identical): elem(gg,tt,rr,kk) at ((gg*32+tt)*16+rr)*32+kk,
// where row = row0 + gg*16 + rr, k = tt*32 + kk.
__device__ __forceinline__ void load_w_lds(const float* W, int row0, u16* wlds, int tid){
  #pragma unroll
  for (int i = 0; i < 16; i++){
    int e = (i * 512 + tid) * 8;
    int R = e >> 10, k = e & 1023;
    int gg = R >> 4, rr = R & 15, tt = k >> 5, kk = k & 31;
    const float* src = W + (size_t)(row0 + gg * 16 + rr) * 1024 + k;
    float4 v0 = *(const float4*)(src);
    float4 v1 = *(const float4*)(src + 4);
    u16* dst = wlds + (((gg * 32 + tt) * 16 + rr) * 32 + kk);
    ushort4 o0, o1;
    o0.x = f2bf(v0.x); o0.y = f2bf(v0.y); o0.z = f2bf(v0.z); o0.w = f2bf(v0.w);
    o1.x = f2bf(v1.x); o1.y = f2bf(v1.y); o1.z = f2bf(v1.z); o1.w = f2bf(v1.w);
    *(ushort4*)dst = o0; *(ushort4*)(dst + 4) = o1;
  }
}

// ---------------- MEGA kernel: lstm (blocks 0-63) + xp producers (64-127)
//                  + ak gemm tiles (128-895), all sharing one dispatch ----------------
// lstm path = r9 verbatim except: xp comes from producer blocks (write-once
// rotating slices, flag-gated; poll merged into the existing wave-0 ballot).

__global__ __launch_bounds__(512, 1) void mega(
  const float* __restrict__ Whh, const float* __restrict__ Wih,
  const float* __restrict__ Wk,
  const u16* __restrict__ x_bf, const u16* __restrict__ keys_bf,
  const float* __restrict__ bsum, const float* __restrict__ nbf,
  u16* __restrict__ xp, u16* __restrict__ akbuf,
  u16* __restrict__ hsteps, u16* __restrict__ qbuf, float* __restrict__ out0,
  int* __restrict__ flags)
{
  extern __shared__ char smem[];
  const int bid = blockIdx.x;
  const int tid = threadIdx.x;
  const int lane = tid & 63, w = tid >> 6;
  const int lr = lane & 15, g = lane >> 4;

  if (bid >= 64){
    // ================= GEMM paths: 8 waves, 64x64 tile, B LDS-resident =========
    u16* wlds = (u16*)smem;
    const int wm = (w >> 2) * 32, wn = (w & 3) * 16, gg = wn >> 4;

    if (bid < 128){
      // ---- xp producer j: xp[step] = x[step] * Wih_rows[j*64,+64)^T + bsum ----
      const int j = bid - 64;
      load_w_lds(Wih, j * 64, wlds, tid);
      __syncthreads();
      const float bv = bsum[j * 64 + wn + lr];
      #pragma unroll 1
      for (int step = 0; step < T_Q; step++){
        f32x4 acc0 = {0,0,0,0}, acc1 = {0,0,0,0};
        const u16* a0p = x_bf + ((size_t)(step * NB) + wm + lr) * 1024 + g * 8;
        const u16* a1p = a0p + (size_t)16 * 1024;
        #pragma unroll 4
        for (int t = 0; t < 32; t++){
          bf16x8 a0 = *(const bf16x8*)(a0p + t * 32);
          bf16x8 a1 = *(const bf16x8*)(a1p + t * 32);
          bf16x8 b  = *(const bf16x8*)(wlds + ((size_t)(gg * 32 + t) * 16 + lr) * 32 + g * 8);
          acc0 = MFMA16(a0, b, acc0);
          acc1 = MFMA16(a1, b, acc1);
        }
        #pragma unroll
        for (int r = 0; r < 4; r++){
          int row0 = wm + g * 4 + r;
          st_b16_cc(xp + ((size_t)(step * NB) + row0) * 4096 + j * 64 + wn + lr,
                    f2bf(acc0[r] + bv));
          st_b16_cc(xp + ((size_t)(step * NB) + row0 + 16) * 4096 + j * 64 + wn + lr,
                    f2bf(acc1[r] + bv));
        }
        asm volatile("s_waitcnt vmcnt(0)" ::: "memory");
        __syncthreads();
        if (tid == 0) st_flag(flags + (64 + j) * 16, step + 1);
      }
    } else {
      // ---- ak tile: ak[by*64.., bx*64..] = keys * Wk_rows[bx*64,+64)^T + nbf ----
      const int t2 = bid - 128;
      const int bx = t2 & 15, by = t2 >> 4;
      load_w_lds(Wk, bx * 64, wlds, tid);
      __syncthreads();
      const float bv = nbf[bx * 64 + wn + lr];
      f32x4 acc0 = {0,0,0,0}, acc1 = {0,0,0,0};
      const u16* a0p = keys_bf + ((size_t)(by * 64) + wm + lr) * 1024 + g * 8;
      const u16* a1p = a0p + (size_t)16 * 1024;
      #pragma unroll 4
      for (int t = 0; t < 32; t++){
        bf16x8 a0 = *(const bf16x8*)(a0p + t * 32);
        bf16x8 a1 = *(const bf16x8*)(a1p + t * 32);
        bf16x8 b  = *(const bf16x8*)(wlds + ((size_t)(gg * 32 + t) * 16 + lr) * 32 + g * 8);
        acc0 = MFMA16(a0, b, acc0);
        acc1 = MFMA16(a1, b, acc1);
      }
      #pragma unroll
      for (int r = 0; r < 4; r++){
        int row0 = by * 64 + wm + g * 4 + r;
        akbuf[(size_t)row0 * 1024 + bx * 64 + wn + lr]        = f2bf(acc0[r] + bv);
        akbuf[(size_t)(row0 + 16) * 1024 + bx * 64 + wn + lr] = f2bf(acc1[r] + bv);
      }
    }
    return;
  }

  // ================= LSTM path (r9 verbatim + producer-xp gating) =================
  u16*  wlds = (u16*)smem;                    // [4][32][16][32] bf16 (128KB)
  float* gl  = (float*)(smem + 131072);       // [4][64][16] f32 (16KB)
  volatile int* lds_ready = (volatile int*)(smem + 147456);  // [8]

  const int c0 = bid * 16;
  const int gate = w & 3, msub = w >> 2;

  if (tid < 8) lds_ready[tid] = 0;

  // one-time: Whh slice (gate-strided rows) f32 -> bf16 -> LDS
  #pragma unroll
  for (int i = 0; i < 16; i++){
    int e = (i * 512 + tid) * 8;
    int R = e >> 10, k = e & 1023;
    int gg = R >> 4, rr = R & 15, tt = k >> 5, kk = k & 31;
    const float* src = Whh + (size_t)((gg << 10) + c0 + rr) * 1024 + k;
    float4 v0 = *(const float4*)(src);
    float4 v1 = *(const float4*)(src + 4);
    u16* dst = wlds + (((gg * 32 + tt) * 16 + rr) * 32 + kk);
    ushort4 o0, o1;
    o0.x = f2bf(v0.x); o0.y = f2bf(v0.y); o0.z = f2bf(v0.z); o0.w = f2bf(v0.w);
    o1.x = f2bf(v1.x); o1.y = f2bf(v1.y); o1.z = f2bf(v1.z); o1.w = f2bf(v1.w);
    *(ushort4*)dst = o0; *(ushort4*)(dst + 4) = o1;
  }
  __syncthreads();

  const int pb = (tid * 2) >> 4;
  const int pc = (tid * 2) & 15;
  float c_state0 = 0.f, c_state1 = 0.f;

  const int arow = msub * 32 + lr;
  const int jc = g >> 1;
  const int cc = (g & 1) * 8;
  // xp producer flags needed by this block: j = lane*16 + (bid>>2) for lane<4
  const int* fxp = flags + (64 + (lane & 3) * 16 + (bid >> 2)) * 16;

#define SPING(gq) \
  do { while (lds_ready[gq] < step) __builtin_amdgcn_s_sleep(1); \
       asm volatile("" ::: "memory"); } while (0)

#define LOADG(s0, s1, gq) \
  do { const u16* A0_ = pa0 + (gq) * 8192; const u16* A1_ = pa1 + (gq) * 8192; \
       s0[0] = *(const bf16x8*)(A0_);        s1[0] = *(const bf16x8*)(A1_); \
       s0[1] = *(const bf16x8*)(A0_ + 2048); s1[1] = *(const bf16x8*)(A1_ + 2048); \
       s0[2] = *(const bf16x8*)(A0_ + 4096); s1[2] = *(const bf16x8*)(A1_ + 4096); \
       s0[3] = *(const bf16x8*)(A0_ + 6144); s1[3] = *(const bf16x8*)(A1_ + 6144); } while (0)

#define MFMAG(s0, s1, gq) \
  do { const u16* wb_ = wlds + ((size_t)(gate * 32 + (gq) * 4) * 16 + lr) * 32 + g * 8; \
       bf16x8 b0_ = *(const bf16x8*)(wb_); \
       bf16x8 b1_ = *(const bf16x8*)(wb_ + 512); \
       bf16x8 b2_ = *(const bf16x8*)(wb_ + 1024); \
       bf16x8 b3_ = *(const bf16x8*)(wb_ + 1536); \
       acc0 = MFMA16(s0[0], b0_, acc0); acc1 = MFMA16(s1[0], b0_, acc1); \
       acc0 = MFMA16(s0[1], b1_, acc0); acc1 = MFMA16(s1[1], b1_, acc1); \
       acc0 = MFMA16(s0[2], b2_, acc0); acc1 = MFMA16(s1[2], b2_, acc1); \
       acc0 = MFMA16(s0[3], b3_, acc0); acc1 = MFMA16(s1[3], b3_, acc1); } while (0)

  #pragma unroll 1
  for (int step = 0; step < T_Q; step++){
    f32x4 acc0 = {0,0,0,0}, acc1 = {0,0,0,0};

    if (step == 0){
      // gate on producer step-0 slices only
      if (w == 0){
        for (;;){
          int f2 = ld_flag(fxp);
          if (__ballot(lane < 4 ? (f2 >= 1) : 1) == ~0ull) break;
          __builtin_amdgcn_s_sleep(1);
        }
      }
    } else {
      // wave 0: sole global poller; h-group signaling + merged xp-flag check
      if (w == 0){
        unsigned done = 0;
        bool xpok = false;
        const int* fp = flags + lane * 16;
        while (done != 0xFFu || !xpok){
          int f = ld_flag(fp);
          unsigned long long b = __ballot(f >= step);
          if (!xpok){
            int f2 = ld_flag(fxp);
            xpok = (__ballot(lane < 4 ? (f2 >= step + 1) : 1) == ~0ull);
          }
          #pragma unroll
          for (int gq = 0; gq < 8; gq++){
            if (((done >> gq) & 1u) == 0 &&
                ((unsigned)(b >> (gq * 8)) & 0xFFu) == 0xFFu){
              if (lane == 0) lds_ready[gq] = step;
              done |= 1u << gq;
            }
          }
          if (done != 0xFFu || !xpok) __builtin_amdgcn_s_sleep(1);
        }
      }

      const u16* hb  = hsteps + (size_t)(step - 1) * 65536;
      const u16* pa0 = hb + (size_t)jc * 1024 + (size_t)arow * 16 + cc;
      const u16* pa1 = pa0 + 256;

      bf16x8 sA0[4], sA1[4], sB0[4], sB1[4];
      SPING(0); LOADG(sA0, sA1, 0);
      SPING(1); LOADG(sB0, sB1, 1); MFMAG(sA0, sA1, 0);
      SPING(2); LOADG(sA0, sA1, 2); MFMAG(sB0, sB1, 1);
      SPING(3); LOADG(sB0, sB1, 3); MFMAG(sA0, sA1, 2);
      SPING(4); LOADG(sA0, sA1, 4); MFMAG(sB0, sB1, 3);
      SPING(5); LOADG(sB0, sB1, 5); MFMAG(sA0, sA1, 4);
      SPING(6); LOADG(sA0, sA1, 6); MFMAG(sB0, sB1, 5);
      SPING(7); LOADG(sB0, sB1, 7); MFMAG(sA0, sA1, 6);
      MFMAG(sB0, sB1, 7);
    }

    // gl exchange. C/D: col=lane&15, row=(lane>>4)*4+reg
    #pragma unroll
    for (int r = 0; r < 4; r++){
      gl[(gate * 64 + msub * 32 +      g * 4 + r) * 16 + lr] = acc0[r];
      gl[(gate * 64 + msub * 32 + 16 + g * 4 + r) * 16 + lr] = acc1[r];
    }
    __syncthreads();                           // also: xp flags confirmed by wave 0

    // xp loads (producer-published, write-once; bias folded in by producer)
    const u16* xr = xp + ((size_t)(step * NB + pb)) * 4096 + c0 + pc;
    unsigned xw0 = *(const unsigned*)(xr);
    unsigned xw1 = *(const unsigned*)(xr + 1024);
    unsigned xw2 = *(const unsigned*)(xr + 2048);
    unsigned xw3 = *(const unsigned*)(xr + 3072);

    float hout0, hout1; u16 hb0, hb1;
    {
      float ig = gl[(0 * 64 + pb) * 16 + pc] + bf2f((u16)(xw0 & 0xFFFF));
      float fg = gl[(1 * 64 + pb) * 16 + pc] + bf2f((u16)(xw1 & 0xFFFF));
      float gg2 = gl[(2 * 64 + pb) * 16 + pc] + bf2f((u16)(xw2 & 0xFFFF));
      float og = gl[(3 * 64 + pb) * 16 + pc] + bf2f((u16)(xw3 & 0xFFFF));
      float cn = sigm(fg) * c_state0 + sigm(ig) * tanh_f(gg2);
      c_state0 = cn;
      hout0 = sigm(og) * tanh_f(cn); hb0 = f2bf(hout0);
    }
    {
      float ig = gl[(0 * 64 + pb) * 16 + pc + 1] + bf2f((u16)(xw0 >> 16));
      float fg = gl[(1 * 64 + pb) * 16 + pc + 1] + bf2f((u16)(xw1 >> 16));
      float gg2 = gl[(2 * 64 + pb) * 16 + pc + 1] + bf2f((u16)(xw2 >> 16));
      float og = gl[(3 * 64 + pb) * 16 + pc + 1] + bf2f((u16)(xw3 >> 16));
      float cn = sigm(fg) * c_state1 + sigm(ig) * tanh_f(gg2);
      c_state1 = cn;
      hout1 = sigm(og) * tanh_f(cn); hb1 = f2bf(hout1);
    }

    if (step < T_Q - 1){
      u16* hw = hsteps + (size_t)step * 65536 + (size_t)bid * 1024 + pb * 16 + pc;
      st_b32_cc(hw, (unsigned)hb0 | ((unsigned)hb1 << 16));
      asm volatile("s_waitcnt vmcnt(0)" ::: "memory");
      __syncthreads();
      if (tid == 0) st_flag(flags + bid * 16, step + 1);
    }

    ushort2 hh; hh.x = hb0; hh.y = hb1;
    *(ushort2*)(qbuf + ((size_t)pb * T_Q + step) * HDIM + c0 + pc) = hh;
    float2 ho; ho.x = hout0; ho.y = hout1;
    *(float2*)(out0 + ((size_t)(step * NB + pb)) * HDIM + c0 + pc) = ho;
  }
#undef SPING
#undef LOADG
#undef MFMAG
}

// ---------------- fused attention: scores -> softmax -> context ----------------

__global__ __launch_bounds__(256) void attn_fused(
  const float* __restrict__ aq, const u16* __restrict__ ak,
  const float* __restrict__ vhat, const u16* __restrict__ keys,
  const int* __restrict__ lens, float* __restrict__ out1)
{
  int b = blockIdx.x >> 5, q = blockIdx.x & 31;
  int t = threadIdx.x, lane = t & 63, w = t >> 6;
  __shared__ float sc[T_K];
  __shared__ float ps[T_K];
  int len = lens[b];
  float aqr[16], vh[16];
  const float* aqp = aq + (size_t)(b * T_Q + q) * HDIM + lane * 16;
  const float* vp  = vhat + lane * 16;
  #pragma unroll
  for (int j = 0; j < 4; j++){
    float4 v0 = ((const float4*)aqp)[j];
    float4 v1 = ((const float4*)vp)[j];
    aqr[j*4+0] = v0.x; aqr[j*4+1] = v0.y; aqr[j*4+2] = v0.z; aqr[j*4+3] = v0.w;
    vh[j*4+0]  = v1.x; vh[j*4+1]  = v1.y; vh[j*4+2]  = v1.z; vh[j*4+3]  = v1.w;
  }

  int kmax = len - w * 12; if (kmax > 12) kmax = 12;
  for (int kk = 0; kk < kmax; kk++){
    int k = w * 12 + kk;
    const u16* akp = ak + (size_t)(k * NB + b) * HDIM + lane * 16;
    us8 a0 = *(const us8*)(akp);
    us8 a1 = *(const us8*)(akp + 8);
    float p = 0.f;
    #pragma unroll
    for (int j = 0; j < 8; j++){
      p += tanh_f(aqr[j]     + bf2f(a0[j])) * vh[j];
      p += tanh_f(aqr[8 + j] + bf2f(a1[j])) * vh[8 + j];
    }
    #pragma unroll
    for (int m = 32; m >= 1; m >>= 1) p += __shfl_xor(p, m);
    if (lane == 0) sc[k] = p;
  }
  __syncthreads();
  float mx = -3.0e38f;
  for (int k = 0; k < len; k++) mx = fmaxf(mx, sc[k]);
  if (t < len) ps[t] = __expf(sc[t] - mx);
  __syncthreads();
  float den = 0.f;
  for (int k = 0; k < len; k++) den += ps[k];
  float rden = __builtin_amdgcn_rcpf(den);

  float c0 = 0.f, c1 = 0.f, c2 = 0.f, c3 = 0.f;
  for (int k = 0; k < len; k++){
    float pk = ps[k];
    ushort4 kv = *(const ushort4*)(keys + (size_t)(k * NB + b) * HDIM + t * 4);
    c0 += pk * bf2f(kv.x); c1 += pk * bf2f(kv.y);
    c2 += pk * bf2f(kv.z); c3 += pk * bf2f(kv.w);
  }
  size_t o = (size_t)(q * NB + b) * HDIM + t * 4;
  out1[o + 0] = c0 * rden;
  out1[o + 1] = c1 * rden;
  out1[o + 2] = c2 * rden;
  out1[o + 3] = c3 * rden;
}

// ---------------- launch ----------------

extern "C" void kernel_launch(void* const* d_in, const int* in_sizes, int n_in,
                              void* d_out, int out_size, void* d_ws, size_t ws_size,
                              hipStream_t stream)
{
  const float* in1  = (const float*)d_in[0];   // input1
  const float* in0  = (const float*)d_in[1];   // input0
  const int*   lens = (const int*)d_in[2];     // input2
  const int*   toks = (const int*)d_in[3];     // input3
  const float* emb  = (const float*)d_in[4];
  const float* Wih  = (const float*)d_in[5];
  const float* Whh  = (const float*)d_in[6];
  const float* bih  = (const float*)d_in[7];
  const float* bhh  = (const float*)d_in[8];
  const float* Wq   = (const float*)d_in[9];
  const float* Wk   = (const float*)d_in[10];
  const float* vatt = (const float*)d_in[11];
  const float* ns   = (const float*)d_in[12];
  const float* nbb  = (const float*)d_in[13];

  char* p = (char*)d_ws;
  u16* x_bf    = (u16*)p;   p += (size_t)2048 * 1024 * 2;   // 4 MB
  u16* keys_bf = (u16*)p;   p += (size_t)3072 * 1024 * 2;   // 6 MB
  u16* hsteps  = (u16*)p;   p += (size_t)32 * 65536 * 2;    // 4 MB rotating h
  u16* qbuf    = (u16*)p;   p += (size_t)2048 * 1024 * 2;   // 4 MB
  u16* xp      = (u16*)p;   p += (size_t)2048 * 4096 * 2;   // 16 MB (dead after mega)
  float* vhat  = (float*)p; p += 1024 * 4;
  float* bsum  = (float*)p; p += 4096 * 4;
  float* nbf   = (float*)p; p += 1024 * 4;
  int* flags   = (int*)p;   p += 8192;                      // 128 flags, 64B apart
  u16* ak      = (u16*)p;   p += (size_t)3072 * 1024 * 2;   // 6 MB
  u16* Wq_bf   = (u16*)p;   p += (size_t)1024 * 1024 * 2;   // 2 MB
  float* aq    = (float*)xp;   // 8 MB, aliases xp (xp dead before aq GEMM)

  float* out0 = (float*)d_out;
  float* out1 = out0 + (size_t)T_Q * NB * HDIM;

  hipMemsetAsync(flags, 0, 8192, stream);

  conv_f2b<<<1024, 256, 0, stream>>>(Wq, Wq_bf);
  gather_x<<<2048, 256, 0, stream>>>(toks, emb, x_bf);
  make_keys<<<3072, 256, 0, stream>>>(in1, in0, keys_bf);
  prep_small<<<1, 256, 0, stream>>>(vatt, ns, nbb, vhat, nbf);
  prep_bsum<<<16, 256, 0, stream>>>(bih, bhh, bsum);

  // mega: lstm (64) + xp producers (64) + ak tiles (768) in one dispatch
  mega<<<896, 512, 147488, stream>>>(Whh, Wih, Wk, x_bf, keys_bf, bsum, nbf,
                                     xp, ak, hsteps, qbuf, out0, flags);

  // aq = q * Wq^T : M=2048, N=1024, K=1024 -> f32 (xp region now dead)
  gemm_bf16<0><<<dim3(16, 32), 256, 0, stream>>>(qbuf, Wq_bf, nullptr, aq, 2048, 1024, 1024);

  attn_fused<<<2048, 256, 0, stream>>>(aq, ak, vhat, keys_bf, lens, out1);
}

// Round 16
// 329.309 us; speedup vs baseline: 2.8616x; 1.6941x over previous
//
#include <hip/hip_runtime.h>
#include <hip/hip_bf16.h>

typedef unsigned short u16;
typedef __attribute__((ext_vector_type(8))) short bf16x8;
typedef __attribute__((ext_vector_type(8))) unsigned short us8;
typedef __attribute__((ext_vector_type(4))) float f32x4;

#define T_Q 32
#define T_K 48
#define NB 64
#define HDIM 1024
#define MASK_FILL -65504.0f
#define LSTM_BLOCKS 64

__device__ __forceinline__ float bf2f(u16 v){
  union { unsigned u; float f; } x; x.u = ((unsigned)v) << 16; return x.f;
}
__device__ __forceinline__ u16 f2bf(float f){
  union { float f; unsigned u; } x; x.f = f;
  return (u16)((x.u + 0x7FFFu + ((x.u >> 16) & 1u)) >> 16);
}
__device__ __forceinline__ float sigm(float x){
  return __builtin_amdgcn_rcpf(1.f + __expf(-x));
}
__device__ __forceinline__ float tanh_f(float x){
  float e = __expf(2.f * x);
  return fmaf(-2.f, __builtin_amdgcn_rcpf(e + 1.f), 1.f);  // graceful at +/-inf
}

// Cross-XCD coherent sync-path ops (sc0 = bypass L0/L1, sc1 = bypass local L2;
// coherence point = Infinity Cache). Used ONLY for the tiny publish/flag path.
// h DATA loads are normal cached loads against write-once rotating buffers (r6).
// Lessons ledger: r7 one-poller; r10 no wave-specialized staging; r11 gemm128
// only where blocks/CU >= 2; r12 no dual-chain; r13/r14/r15 no work-fusion or
// co-launch on/next to the lstm critical path.
__device__ __forceinline__ void st_b32_cc(u16* a, unsigned v){
  asm volatile("global_store_dword %0, %1, off sc0 sc1" :: "v"(a), "v"(v) : "memory");
}
__device__ __forceinline__ void st_flag(int* a, int v){
  asm volatile("global_store_dword %0, %1, off sc0 sc1" :: "v"(a), "v"(v) : "memory");
}
__device__ __forceinline__ int ld_flag(const int* a){
  int r;
  asm volatile("global_load_dword %0, %1, off sc0 sc1\n\ts_waitcnt vmcnt(0)"
               : "=v"(r) : "v"(a) : "memory");
  return r;
}

#define MFMA16(A,B,C) __builtin_amdgcn_mfma_f32_16x16x32_bf16(A,B,C,0,0,0)

// ---------------- prep kernels ----------------

__global__ void conv_f2b(const float* __restrict__ s, u16* __restrict__ d){
  size_t i = ((size_t)blockIdx.x * 256 + threadIdx.x) * 4;
  float4 v = *(const float4*)(s + i);
  ushort4 o; o.x = f2bf(v.x); o.y = f2bf(v.y); o.z = f2bf(v.z); o.w = f2bf(v.w);
  *(ushort4*)(d + i) = o;
}

__global__ void gather_x(const int* __restrict__ tok, const float* __restrict__ emb,
                         u16* __restrict__ x){
  int r = blockIdx.x;                      // r = t*64 + b
  int token = tok[r];
  float4 v = ((const float4*)(emb + (size_t)token * HDIM))[threadIdx.x];
  ushort4 o; o.x = f2bf(v.x); o.y = f2bf(v.y); o.z = f2bf(v.z); o.w = f2bf(v.w);
  ((ushort4*)(x + (size_t)r * HDIM))[threadIdx.x] = o;
}

__global__ void make_keys(const float* __restrict__ a, const float* __restrict__ b,
                          u16* __restrict__ o){
  size_t i = ((size_t)blockIdx.x * 256 + threadIdx.x) * 4;
  float4 va = *(const float4*)(a + i);
  float4 vb = *(const float4*)(b + i);
  ushort4 vo;
  vo.x = f2bf(va.x + vb.x);
  vo.y = f2bf(va.y + vb.y);
  vo.z = f2bf(va.z + vb.z);
  vo.w = f2bf(va.w + vb.w);
  *(ushort4*)(o + i) = vo;
}

__global__ void prep_small(const float* __restrict__ vatt, const float* __restrict__ ns,
                           const float* __restrict__ nb,
                           float* __restrict__ vhat, float* __restrict__ nbias){
  __shared__ float wred[4];
  int t = threadIdx.x, lane = t & 63, w = t >> 6;
  float vv[4]; float s = 0.f;
  #pragma unroll
  for (int j = 0; j < 4; j++){ vv[j] = vatt[t*4 + j]; s += vv[j]*vv[j]; }
  #pragma unroll
  for (int m = 32; m >= 1; m >>= 1) s += __shfl_xor(s, m);
  if (lane == 0) wred[w] = s;
  __syncthreads();
  float tot = wred[0] + wred[1] + wred[2] + wred[3];
  float scale = ns[0] / sqrtf(tot);
  #pragma unroll
  for (int j = 0; j < 4; j++) vhat[t*4 + j] = vv[j] * scale;
  #pragma unroll
  for (int j = 0; j < 4; j++){ int i = t + 256*j; nbias[i] = nb[i]; }
}

__global__ void prep_bsum(const float* __restrict__ bih, const float* __restrict__ bhh,
                          float* __restrict__ bias_sum){
  int i = blockIdx.x * 256 + threadIdx.x;
  bias_sum[i] = bih[i] + bhh[i];
}

// ---------------- generic bf16 GEMM (r6/r9-proven 64x64 tile) ----------------
// C[M][N] = A[M][K] * W[N][K]^T + bias. OB=1 -> bf16 out, OB=0 -> f32 out.
// Use when grid would be < 2 blocks/CU with a 128-tile (r11 lesson).

template<int OB>
__global__ __launch_bounds__(256) void gemm_bf16(
  const u16* __restrict__ A, const u16* __restrict__ W,
  const float* __restrict__ bias, void* __restrict__ Cv,
  int M, int N, int K)
{
  __shared__ __align__(16) u16 As[4][66][8];   // [kc][row][8], kc-stride 1056B
  __shared__ __align__(16) u16 Bs[4][66][8];
  const int t = threadIdx.x;
  const int m0 = blockIdx.y * 64, n0 = blockIdx.x * 64;
  const int lane = t & 63, w = t >> 6;
  const int wm = (w >> 1) * 32, wn = (w & 1) * 32;
  const int lr = lane & 15, g = lane >> 4;
  const int lrow = t >> 2, lkc = t & 3;
  f32x4 acc00 = {0,0,0,0}, acc01 = {0,0,0,0}, acc10 = {0,0,0,0}, acc11 = {0,0,0,0};
  const u16* aptr = A + (size_t)(m0 + lrow) * K + lkc * 8;
  const u16* wptr = W + (size_t)(n0 + lrow) * K + lkc * 8;
  for (int k0 = 0; k0 < K; k0 += 32){
    *(bf16x8*)(&As[lkc][lrow][0]) = *(const bf16x8*)(aptr + k0);
    *(bf16x8*)(&Bs[lkc][lrow][0]) = *(const bf16x8*)(wptr + k0);
    __syncthreads();
    bf16x8 a0 = *(const bf16x8*)(&As[g][wm      + lr][0]);
    bf16x8 a1 = *(const bf16x8*)(&As[g][wm + 16 + lr][0]);
    bf16x8 b0 = *(const bf16x8*)(&Bs[g][wn      + lr][0]);
    bf16x8 b1 = *(const bf16x8*)(&Bs[g][wn + 16 + lr][0]);
    acc00 = MFMA16(a0, b0, acc00);
    acc01 = MFMA16(a0, b1, acc01);
    acc10 = MFMA16(a1, b0, acc10);
    acc11 = MFMA16(a1, b1, acc11);
    __syncthreads();
  }
  // C/D layout: col = lane&15, row = (lane>>4)*4 + reg   [m89-verified]
  const int rb = m0 + wm + g * 4;
  const int cb = n0 + wn + lr;
  float bv0 = bias ? bias[cb]      : 0.f;
  float bv1 = bias ? bias[cb + 16] : 0.f;
  #pragma unroll
  for (int r = 0; r < 4; r++){
    float v00 = acc00[r] + bv0, v01 = acc01[r] + bv1;
    float v10 = acc10[r] + bv0, v11 = acc11[r] + bv1;
    if (OB){
      u16* C = (u16*)Cv;
      C[(size_t)(rb + r)      * N + cb]      = f2bf(v00);
      C[(size_t)(rb + r)      * N + cb + 16] = f2bf(v01);
      C[(size_t)(rb + 16 + r) * N + cb]      = f2bf(v10);
      C[(size_t)(rb + 16 + r) * N + cb + 16] = f2bf(v11);
    } else {
      float* C = (float*)Cv;
      C[(size_t)(rb + r)      * N + cb]      = v00;
      C[(size_t)(rb + r)      * N + cb + 16] = v01;
      C[(size_t)(rb + 16 + r) * N + cb]      = v10;
      C[(size_t)(rb + 16 + r) * N + cb + 16] = v11;
    }
  }
}

// ---------------- 128x128-tile bf16 GEMM (r11 padded version, passed 2x) ---------
// Only used where grid >= 2 blocks/CU (xp: 512 blocks). Rows padded to 40 elems
// (80B) -> fragment reads spread 2 lanes/bank (free). OB=1 bf16 out.

template<int OB>
__global__ __launch_bounds__(256) void gemm128(
  const u16* __restrict__ A, const u16* __restrict__ W,
  const float* __restrict__ bias, void* __restrict__ Cv,
  int M, int N, int K)
{
  __shared__ __align__(16) u16 As[128][40];
  __shared__ __align__(16) u16 Bs[128][40];
  const int t = threadIdx.x;
  const int m0 = blockIdx.y * 128, n0 = blockIdx.x * 128;
  const int lane = t & 63, w = t >> 6;
  const int wm = (w >> 1) * 64, wn = (w & 1) * 64;
  const int lr = lane & 15, g = lane >> 4;
  const int srow = t >> 2, skc = t & 3;

  f32x4 acc[4][4];
  #pragma unroll
  for (int i = 0; i < 4; i++)
    #pragma unroll
    for (int j = 0; j < 4; j++) acc[i][j] = (f32x4){0,0,0,0};

  const u16* aptr0 = A + (size_t)(m0 + srow)      * K + skc * 8;
  const u16* aptr1 = A + (size_t)(m0 + 64 + srow) * K + skc * 8;
  const u16* wptr0 = W + (size_t)(n0 + srow)      * K + skc * 8;
  const u16* wptr1 = W + (size_t)(n0 + 64 + srow) * K + skc * 8;

  for (int k0 = 0; k0 < K; k0 += 32){
    bf16x8 va0 = *(const bf16x8*)(aptr0 + k0);
    bf16x8 va1 = *(const bf16x8*)(aptr1 + k0);
    bf16x8 vb0 = *(const bf16x8*)(wptr0 + k0);
    bf16x8 vb1 = *(const bf16x8*)(wptr1 + k0);
    *(bf16x8*)(&As[srow][skc * 8])      = va0;
    *(bf16x8*)(&As[64 + srow][skc * 8]) = va1;
    *(bf16x8*)(&Bs[srow][skc * 8])      = vb0;
    *(bf16x8*)(&Bs[64 + srow][skc * 8]) = vb1;
    __syncthreads();
    bf16x8 af[4], bfr[4];
    #pragma unroll
    for (int mi = 0; mi < 4; mi++) af[mi]  = *(const bf16x8*)(&As[wm + mi * 16 + lr][g * 8]);
    #pragma unroll
    for (int ni = 0; ni < 4; ni++) bfr[ni] = *(const bf16x8*)(&Bs[wn + ni * 16 + lr][g * 8]);
    #pragma unroll
    for (int mi = 0; mi < 4; mi++)
      #pragma unroll
      for (int ni = 0; ni < 4; ni++)
        acc[mi][ni] = MFMA16(af[mi], bfr[ni], acc[mi][ni]);
    __syncthreads();
  }

  // C/D layout: col = lane&15, row = (lane>>4)*4 + reg   [m89-verified, r8/r11-passed]
  float bv[4];
  #pragma unroll
  for (int ni = 0; ni < 4; ni++) bv[ni] = bias ? bias[n0 + wn + ni * 16 + lr] : 0.f;
  #pragma unroll
  for (int mi = 0; mi < 4; mi++){
    #pragma unroll
    for (int r = 0; r < 4; r++){
      const size_t row = (size_t)(m0 + wm + mi * 16 + g * 4 + r);
      #pragma unroll
      for (int ni = 0; ni < 4; ni++){
        float v = acc[mi][ni][r] + bv[ni];
        const size_t col = (size_t)(n0 + wn + ni * 16 + lr);
        if (OB) ((u16*)Cv)[row * N + col] = f2bf(v);
        else    ((float*)Cv)[row * N + col] = v;
      }
    }
  }
}

// ---------------- persistent LSTM (r9 verbatim -- best measured, 201us) ----------------
// 64 blocks x 512 threads. Block j owns h-cols [j*16, j*16+16) for all 4 gates.
// Whh slice (f32->bf16) resident in LDS; c-state in registers.
// h exchange: write-once rotating buffers + per-block flags; wave 0 = sole
// global poller, marks producer-groups ready via LDS; waves consume groups
// as they land.

__global__ __launch_bounds__(512, 1) void lstm_persistent(
  const float* __restrict__ Whh, const u16* __restrict__ xp,
  u16* __restrict__ hsteps,
  u16* __restrict__ qbuf, float* __restrict__ out0,
  int* __restrict__ flags)
{
  extern __shared__ char smem[];
  u16*  wlds = (u16*)smem;                    // [4][32][16][32] bf16 (128KB)
  float* gl  = (float*)(smem + 131072);       // [4][64][16] f32 (16KB)
  volatile int* lds_ready = (volatile int*)(smem + 147456);  // [8]

  const int tid = threadIdx.x;
  const int c0 = blockIdx.x * 16;
  const int lane = tid & 63, w = tid >> 6;    // 8 waves
  const int gate = w & 3, msub = w >> 2;      // wave -> (gate, m-half)
  const int lr = lane & 15, g = lane >> 4;

  if (tid < 8) lds_ready[tid] = 0;

  // ---- one-time: Whh slice f32 -> bf16 -> LDS ----
  #pragma unroll
  for (int i = 0; i < 16; i++){
    int e = (i * 512 + tid) * 8;               // element in 64x1024 slice
    int R = e >> 10, k = e & 1023;
    int gg = R >> 4, rr = R & 15, tt = k >> 5, kk = k & 31;
    const float* src = Whh + (size_t)((gg << 10) + c0 + rr) * 1024 + k;
    float4 v0 = *(const float4*)(src);
    float4 v1 = *(const float4*)(src + 4);
    u16* dst = wlds + (((gg * 32 + tt) * 16 + rr) * 32 + kk);
    ushort4 o0, o1;
    o0.x = f2bf(v0.x); o0.y = f2bf(v0.y); o0.z = f2bf(v0.z); o0.w = f2bf(v0.w);
    o1.x = f2bf(v1.x); o1.y = f2bf(v1.y); o1.z = f2bf(v1.z); o1.w = f2bf(v1.w);
    *(ushort4*)dst = o0; *(ushort4*)(dst + 4) = o1;
  }
  __syncthreads();

  // pointwise ownership: 2 cells/thread
  const int pb = (tid * 2) >> 4;               // batch 0..63
  const int pc = (tid * 2) & 15;               // col pair base (even)
  float c_state0 = 0.f, c_state1 = 0.f;

  const int arow = msub * 32 + lr;             // batch rows for this wave's m-tiles
  // h layout: elem(step,row,k) = step*65536 + (k>>4)*1024 + row*16 + (k&15)
  const int jc = g >> 1;
  const int cc = (g & 1) * 8;

// group gq = k-tiles [gq*4, gq*4+4) = producer blocks [gq*8, gq*8+8)
#define SPING(gq) \
  do { while (lds_ready[gq] < step) __builtin_amdgcn_s_sleep(1); \
       asm volatile("" ::: "memory"); } while (0)

#define LOADG(s0, s1, gq) \
  do { const u16* A0_ = pa0 + (gq) * 8192; const u16* A1_ = pa1 + (gq) * 8192; \
       s0[0] = *(const bf16x8*)(A0_);        s1[0] = *(const bf16x8*)(A1_); \
       s0[1] = *(const bf16x8*)(A0_ + 2048); s1[1] = *(const bf16x8*)(A1_ + 2048); \
       s0[2] = *(const bf16x8*)(A0_ + 4096); s1[2] = *(const bf16x8*)(A1_ + 4096); \
       s0[3] = *(const bf16x8*)(A0_ + 6144); s1[3] = *(const bf16x8*)(A1_ + 6144); } while (0)

#define MFMAG(s0, s1, gq) \
  do { const u16* wb_ = wlds + ((size_t)(gate * 32 + (gq) * 4) * 16 + lr) * 32 + g * 8; \
       bf16x8 b0_ = *(const bf16x8*)(wb_); \
       bf16x8 b1_ = *(const bf16x8*)(wb_ + 512); \
       bf16x8 b2_ = *(const bf16x8*)(wb_ + 1024); \
       bf16x8 b3_ = *(const bf16x8*)(wb_ + 1536); \
       acc0 = MFMA16(s0[0], b0_, acc0); acc1 = MFMA16(s1[0], b0_, acc1); \
       acc0 = MFMA16(s0[1], b1_, acc0); acc1 = MFMA16(s1[1], b1_, acc1); \
       acc0 = MFMA16(s0[2], b2_, acc0); acc1 = MFMA16(s1[2], b2_, acc1); \
       acc0 = MFMA16(s0[3], b3_, acc0); acc1 = MFMA16(s1[3], b3_, acc1); } while (0)

  #pragma unroll 1
  for (int step = 0; step < T_Q; step++){
    // xp loads first: latency hides in the wait (pinned by ld_flag/spin barriers)
    const u16* xr = xp + ((size_t)(step * NB + pb)) * 4096 + c0 + pc;
    unsigned xw0 = *(const unsigned*)(xr);
    unsigned xw1 = *(const unsigned*)(xr + 1024);
    unsigned xw2 = *(const unsigned*)(xr + 2048);
    unsigned xw3 = *(const unsigned*)(xr + 3072);

    f32x4 acc0 = {0,0,0,0}, acc1 = {0,0,0,0};

    if (step > 0){
      // ---- wave 0: sole global poller; signals per-group readiness via LDS ----
      if (w == 0){
        unsigned done = 0;
        const int* fp = flags + lane * 16;
        while (done != 0xFFu){
          int f = ld_flag(fp);
          unsigned long long b = __ballot(f >= step);
          #pragma unroll
          for (int gq = 0; gq < 8; gq++){
            if (((done >> gq) & 1u) == 0 &&
                ((unsigned)(b >> (gq * 8)) & 0xFFu) == 0xFFu){
              if (lane == 0) lds_ready[gq] = step;
              done |= 1u << gq;
            }
          }
          if (done != 0xFFu) __builtin_amdgcn_s_sleep(1);
        }
      }

      const u16* hb  = hsteps + (size_t)(step - 1) * 65536;
      const u16* pa0 = hb + (size_t)jc * 1024 + (size_t)arow * 16 + cc;
      const u16* pa1 = pa0 + 256;              // rows arow+16

      bf16x8 sA0[4], sA1[4], sB0[4], sB1[4];
      SPING(0); LOADG(sA0, sA1, 0);
      SPING(1); LOADG(sB0, sB1, 1); MFMAG(sA0, sA1, 0);
      SPING(2); LOADG(sA0, sA1, 2); MFMAG(sB0, sB1, 1);
      SPING(3); LOADG(sB0, sB1, 3); MFMAG(sA0, sA1, 2);
      SPING(4); LOADG(sA0, sA1, 4); MFMAG(sB0, sB1, 3);
      SPING(5); LOADG(sB0, sB1, 5); MFMAG(sA0, sA1, 4);
      SPING(6); LOADG(sA0, sA1, 6); MFMAG(sB0, sB1, 5);
      SPING(7); LOADG(sB0, sB1, 7); MFMAG(sA0, sA1, 6);
      MFMAG(sB0, sB1, 7);
    }

    // gate preacts -> LDS exchange. C/D: col=lane&15, row=(lane>>4)*4+reg
    #pragma unroll
    for (int r = 0; r < 4; r++){
      gl[(gate * 64 + msub * 32 +      g * 4 + r) * 16 + lr] = acc0[r];
      gl[(gate * 64 + msub * 32 + 16 + g * 4 + r) * 16 + lr] = acc1[r];
    }
    __syncthreads();

    // pointwise: 2 cells (pb, pc) (pb, pc+1)
    float hout0, hout1; u16 hb0, hb1;
    {
      float ig = gl[(0 * 64 + pb) * 16 + pc] + bf2f((u16)(xw0 & 0xFFFF));
      float fg = gl[(1 * 64 + pb) * 16 + pc] + bf2f((u16)(xw1 & 0xFFFF));
      float gg = gl[(2 * 64 + pb) * 16 + pc] + bf2f((u16)(xw2 & 0xFFFF));
      float og = gl[(3 * 64 + pb) * 16 + pc] + bf2f((u16)(xw3 & 0xFFFF));
      float cn = sigm(fg) * c_state0 + sigm(ig) * tanh_f(gg);
      c_state0 = cn;
      hout0 = sigm(og) * tanh_f(cn); hb0 = f2bf(hout0);
    }
    {
      float ig = gl[(0 * 64 + pb) * 16 + pc + 1] + bf2f((u16)(xw0 >> 16));
      float fg = gl[(1 * 64 + pb) * 16 + pc + 1] + bf2f((u16)(xw1 >> 16));
      float gg = gl[(2 * 64 + pb) * 16 + pc + 1] + bf2f((u16)(xw2 >> 16));
      float og = gl[(3 * 64 + pb) * 16 + pc + 1] + bf2f((u16)(xw3 >> 16));
      float cn = sigm(fg) * c_state1 + sigm(ig) * tanh_f(gg);
      c_state1 = cn;
      hout1 = sigm(og) * tanh_f(cn); hb1 = f2bf(hout1);
    }

    if (step < T_Q - 1){
      // publish h_step into block-contiguous region, then flag. One dword/thread.
      u16* hw = hsteps + (size_t)step * 65536 + (size_t)blockIdx.x * 1024 + pb * 16 + pc;
      unsigned hpack = (unsigned)hb0 | ((unsigned)hb1 << 16);
      st_b32_cc(hw, hpack);
      asm volatile("s_waitcnt vmcnt(0)" ::: "memory");
      __syncthreads();                          // whole block's h is at L3
      if (tid == 0) st_flag(flags + blockIdx.x * 16, step + 1);
    }

    ushort2 hh; hh.x = hb0; hh.y = hb1;
    *(ushort2*)(qbuf + ((size_t)pb * T_Q + step) * HDIM + c0 + pc) = hh;
    float2 ho; ho.x = hout0; ho.y = hout1;
    *(float2*)(out0 + ((size_t)(step * NB + pb)) * HDIM + c0 + pc) = ho;
  }
#undef SPING
#undef LOADG
#undef MFMAG
}

// ---------------- fused attention: scores -> softmax -> context ----------------
// block per (b,q). wave w handles keys k in [w*12, min(len,w*12+12)). len-bounded.

__global__ __launch_bounds__(256) void attn_fused(
  const float* __restrict__ aq, const u16* __restrict__ ak,
  const float* __restrict__ vhat, const u16* __restrict__ keys,
  const int* __restrict__ lens, float* __restrict__ out1)
{
  int b = blockIdx.x >> 5, q = blockIdx.x & 31;
  int t = threadIdx.x, lane = t & 63, w = t >> 6;
  __shared__ float sc[T_K];
  __shared__ float ps[T_K];
  int len = lens[b];
  float aqr[16], vh[16];
  const float* aqp = aq + (size_t)(b * T_Q + q) * HDIM + lane * 16;
  const float* vp  = vhat + lane * 16;
  #pragma unroll
  for (int j = 0; j < 4; j++){
    float4 v0 = ((const float4*)aqp)[j];
    float4 v1 = ((const float4*)vp)[j];
    aqr[j*4+0] = v0.x; aqr[j*4+1] = v0.y; aqr[j*4+2] = v0.z; aqr[j*4+3] = v0.w;
    vh[j*4+0]  = v1.x; vh[j*4+1]  = v1.y; vh[j*4+2]  = v1.z; vh[j*4+3]  = v1.w;
  }

  int kmax = len - w * 12; if (kmax > 12) kmax = 12;
  for (int kk = 0; kk < kmax; kk++){
    int k = w * 12 + kk;
    const u16* akp = ak + (size_t)(k * NB + b) * HDIM + lane * 16;
    us8 a0 = *(const us8*)(akp);
    us8 a1 = *(const us8*)(akp + 8);
    float p = 0.f;
    #pragma unroll
    for (int j = 0; j < 8; j++){
      p += tanh_f(aqr[j]     + bf2f(a0[j])) * vh[j];
      p += tanh_f(aqr[8 + j] + bf2f(a1[j])) * vh[8 + j];
    }
    #pragma unroll
    for (int m = 32; m >= 1; m >>= 1) p += __shfl_xor(p, m);
    if (lane == 0) sc[k] = p;
  }
  __syncthreads();
  float mx = -3.0e38f;
  for (int k = 0; k < len; k++) mx = fmaxf(mx, sc[k]);
  if (t < len) ps[t] = __expf(sc[t] - mx);
  __syncthreads();
  float den = 0.f;
  for (int k = 0; k < len; k++) den += ps[k];
  float rden = __builtin_amdgcn_rcpf(den);

  float c0 = 0.f, c1 = 0.f, c2 = 0.f, c3 = 0.f;
  for (int k = 0; k < len; k++){
    float pk = ps[k];
    ushort4 kv = *(const ushort4*)(keys + (size_t)(k * NB + b) * HDIM + t * 4);
    c0 += pk * bf2f(kv.x); c1 += pk * bf2f(kv.y);
    c2 += pk * bf2f(kv.z); c3 += pk * bf2f(kv.w);
  }
  size_t o = (size_t)(q * NB + b) * HDIM + t * 4;
  out1[o + 0] = c0 * rden;
  out1[o + 1] = c1 * rden;
  out1[o + 2] = c2 * rden;
  out1[o + 3] = c3 * rden;
}

// ---------------- launch ----------------

extern "C" void kernel_launch(void* const* d_in, const int* in_sizes, int n_in,
                              void* d_out, int out_size, void* d_ws, size_t ws_size,
                              hipStream_t stream)
{
  const float* in1  = (const float*)d_in[0];   // input1
  const float* in0  = (const float*)d_in[1];   // input0
  const int*   lens = (const int*)d_in[2];     // input2
  const int*   toks = (const int*)d_in[3];     // input3
  const float* emb  = (const float*)d_in[4];
  const float* Wih  = (const float*)d_in[5];
  const float* Whh  = (const float*)d_in[6];
  const float* bih  = (const float*)d_in[7];
  const float* bhh  = (const float*)d_in[8];
  const float* Wq   = (const float*)d_in[9];
  const float* Wk   = (const float*)d_in[10];
  const float* vatt = (const float*)d_in[11];
  const float* ns   = (const float*)d_in[12];
  const float* nbb  = (const float*)d_in[13];

  char* p = (char*)d_ws;
  u16* x_bf    = (u16*)p;   p += (size_t)2048 * 1024 * 2;   // 4 MB
  u16* keys_bf = (u16*)p;   p += (size_t)3072 * 1024 * 2;   // 6 MB
  u16* hsteps  = (u16*)p;   p += (size_t)32 * 65536 * 2;    // 4 MB rotating h
  u16* qbuf    = (u16*)p;   p += (size_t)2048 * 1024 * 2;   // 4 MB
  u16* xp      = (u16*)p;   p += (size_t)2048 * 4096 * 2;   // 16 MB (dead after LSTM)
  float* vhat  = (float*)p; p += 1024 * 4;
  float* bsum  = (float*)p; p += 4096 * 4;
  float* nbf   = (float*)p; p += 1024 * 4;
  int* flags   = (int*)p;   p += 4096;                      // 64 flags, 64B apart
  u16* ak      = (u16*)p;   p += (size_t)3072 * 1024 * 2;   // 6 MB
  u16* Wih_bf  = (u16*)p;   p += (size_t)4096 * 1024 * 2;   // 8 MB
  u16* Wq_bf   = (u16*)p;   p += (size_t)1024 * 1024 * 2;   // 2 MB
  u16* Wk_bf   = (u16*)p;   p += (size_t)1024 * 1024 * 2;   // 2 MB
  float* aq    = (float*)xp;   // 8 MB, aliases xp (xp fully consumed before aq GEMM)

  float* out0 = (float*)d_out;
  float* out1 = out0 + (size_t)T_Q * NB * HDIM;

  hipMemsetAsync(flags, 0, 4096, stream);

  conv_f2b<<<4096, 256, 0, stream>>>(Wih, Wih_bf);
  conv_f2b<<<1024, 256, 0, stream>>>(Wq,  Wq_bf);
  conv_f2b<<<1024, 256, 0, stream>>>(Wk,  Wk_bf);
  gather_x<<<2048, 256, 0, stream>>>(toks, emb, x_bf);
  make_keys<<<3072, 256, 0, stream>>>(in1, in0, keys_bf);
  prep_small<<<1, 256, 0, stream>>>(vatt, ns, nbb, vhat, nbf);
  prep_bsum<<<16, 256, 0, stream>>>(bih, bhh, bsum);

  // xp = x * Wih^T + (bih + bhh) : M=2048, N=4096, K=1024 -> bf16
  // 128-tile: 512 blocks = 2/CU (r11 lesson: only use 128-tile at >=2 blocks/CU)
  gemm128<1><<<dim3(32, 16), 256, 0, stream>>>(x_bf, Wih_bf, bsum, xp, 2048, 4096, 1024);
  // ak = keys * Wk^T + norm_bias : M=3072, N=1024, K=1024 -> bf16 (64-tile, 768 blocks)
  gemm_bf16<1><<<dim3(16, 48), 256, 0, stream>>>(keys_bf, Wk_bf, nbf, ak, 3072, 1024, 1024);

  // all 32 LSTM steps in one persistent kernel (144KB+32B dynamic LDS, 1 block/CU)
  lstm_persistent<<<LSTM_BLOCKS, 512, 147488, stream>>>(Whh, xp, hsteps, qbuf, out0, flags);

  // aq = q * Wq^T : M=2048, N=1024, K=1024 -> f32 (64-tile, 512 blocks)
  gemm_bf16<0><<<dim3(16, 32), 256, 0, stream>>>(qbuf, Wq_bf, nullptr, aq, 2048, 1024, 1024);

  attn_fused<<<2048, 256, 0, stream>>>(aq, ak, vhat, keys_bf, lens, out1);
}